// Round 1
// baseline (1267.357 us; speedup 1.0000x reference)
//
#include <hip/hip_runtime.h>
#include <math.h>

#define BB 4
#define NN 1024
#define DD 512
#define HH 8
#define UVQK_C 2048
#define ROWS (BB * NN)   // 4096
#define NBL 4

__device__ __forceinline__ float silu_f(float x) {
    return x / (1.0f + expf(-x));
}

// ---------------------------------------------------------------- init
// x = (seq * sqrt(512) + pos_embed) * mask
__global__ __launch_bounds__(128) void k_init(const float* __restrict__ seq,
                                              const float* __restrict__ pos,
                                              const int* __restrict__ slen,
                                              float* __restrict__ x) {
    int row = blockIdx.x;                 // b*N + n
    int b = row >> 10, n = row & (NN - 1);
    float m = (n < slen[b]) ? 1.0f : 0.0f;
    int c = threadIdx.x << 2;
    float4 s4 = *(const float4*)&seq[(size_t)row * DD + c];
    float4 p4 = *(const float4*)&pos[(size_t)n * DD + c];
    const float SD = 22.627416997969522f;  // sqrt(512)
    float4 o;
    o.x = (s4.x * SD + p4.x) * m;
    o.y = (s4.y * SD + p4.y) * m;
    o.z = (s4.z * SD + p4.z) * m;
    o.w = (s4.w * SD + p4.w) * m;
    *(float4*)&x[(size_t)row * DD + c] = o;
}

// ---------------------------------------------------------------- layernorm
// O[row] = LN(X[row]) * g + b   (optionally * U[row] with stride 2048)
__global__ __launch_bounds__(256) void k_ln(const float* __restrict__ X,
                                            const float* __restrict__ g,
                                            const float* __restrict__ bt,
                                            float* __restrict__ O,
                                            const float* __restrict__ U) {
    __shared__ float sbuf[4];
    int row = blockIdx.x;
    int c = threadIdx.x << 1;
    float2 v = *(const float2*)&X[(size_t)row * 512 + c];

    float s = v.x + v.y;
    #pragma unroll
    for (int off = 1; off < 64; off <<= 1) s += __shfl_xor(s, off);
    if ((threadIdx.x & 63) == 0) sbuf[threadIdx.x >> 6] = s;
    __syncthreads();
    s = sbuf[0] + sbuf[1] + sbuf[2] + sbuf[3];
    float mu = s * (1.0f / 512.0f);
    float dx = v.x - mu, dy = v.y - mu;
    float ss = dx * dx + dy * dy;
    __syncthreads();  // sbuf reuse
    #pragma unroll
    for (int off = 1; off < 64; off <<= 1) ss += __shfl_xor(ss, off);
    if ((threadIdx.x & 63) == 0) sbuf[threadIdx.x >> 6] = ss;
    __syncthreads();
    ss = sbuf[0] + sbuf[1] + sbuf[2] + sbuf[3];
    float rs = rsqrtf(ss * (1.0f / 512.0f) + 1e-6f);

    float o0 = dx * rs * g[c] + bt[c];
    float o1 = dy * rs * g[c + 1] + bt[c + 1];
    if (U) {
        o0 *= U[(size_t)row * UVQK_C + c];
        o1 *= U[(size_t)row * UVQK_C + c + 1];
    }
    O[(size_t)row * 512 + c] = o0;
    O[(size_t)row * 512 + c + 1] = o1;
}

// ---------------------------------------------------------------- GEMM + silu
// C[4096 x Nc] = silu(A[4096 x K] @ Bw[K x Nc])
__global__ __launch_bounds__(256) void k_gemm_silu(const float* __restrict__ A,
                                                   const float* __restrict__ Bw,
                                                   float* __restrict__ C,
                                                   int Nc, int K) {
    __shared__ float As[16][64];  // [kk][i]
    __shared__ float Bs[16][64];  // [kk][j]
    int tid = threadIdx.x;
    int tx = tid & 15, ty = tid >> 4;
    int row0 = blockIdx.y << 6, col0 = blockIdx.x << 6;
    int ar = tid >> 2, ac = (tid & 3) << 2;   // A tile: 64 rows x 16 k
    int bk = tid >> 4, bc = (tid & 15) << 2;  // B tile: 16 k x 64 cols
    float acc[4][4] = {};
    for (int k0 = 0; k0 < K; k0 += 16) {
        float4 a4 = *(const float4*)&A[(size_t)(row0 + ar) * K + k0 + ac];
        float4 b4 = *(const float4*)&Bw[(size_t)(k0 + bk) * Nc + col0 + bc];
        __syncthreads();
        As[ac + 0][ar] = a4.x; As[ac + 1][ar] = a4.y;
        As[ac + 2][ar] = a4.z; As[ac + 3][ar] = a4.w;
        *(float4*)&Bs[bk][bc] = b4;
        __syncthreads();
        #pragma unroll
        for (int kk = 0; kk < 16; ++kk) {
            float a[4], bb[4];
            #pragma unroll
            for (int i = 0; i < 4; ++i) a[i] = As[kk][(ty << 2) + i];
            #pragma unroll
            for (int j = 0; j < 4; ++j) bb[j] = Bs[kk][(tx << 2) + j];
            #pragma unroll
            for (int i = 0; i < 4; ++i)
                #pragma unroll
                for (int j = 0; j < 4; ++j)
                    acc[i][j] = fmaf(a[i], bb[j], acc[i][j]);
        }
    }
    #pragma unroll
    for (int i = 0; i < 4; ++i) {
        int row = row0 + (ty << 2) + i;
        float4 o;
        o.x = silu_f(acc[i][0]); o.y = silu_f(acc[i][1]);
        o.z = silu_f(acc[i][2]); o.w = silu_f(acc[i][3]);
        *(float4*)&C[(size_t)row * Nc + col0 + (tx << 2)] = o;
    }
}

// ---------------------------------------------------------------- GEMM + residual + mask
// X = (X + A @ Bw + bo) * mask   (in place, Nc = K = 512)
__global__ __launch_bounds__(256) void k_gemm_out(const float* __restrict__ A,
                                                  const float* __restrict__ Bw,
                                                  const float* __restrict__ bo,
                                                  const int* __restrict__ slen,
                                                  float* __restrict__ X) {
    __shared__ float As[16][64];
    __shared__ float Bs[16][64];
    int tid = threadIdx.x;
    int tx = tid & 15, ty = tid >> 4;
    int row0 = blockIdx.y << 6, col0 = blockIdx.x << 6;
    int ar = tid >> 2, ac = (tid & 3) << 2;
    int bk = tid >> 4, bc = (tid & 15) << 2;
    float acc[4][4] = {};
    for (int k0 = 0; k0 < 512; k0 += 16) {
        float4 a4 = *(const float4*)&A[(size_t)(row0 + ar) * 512 + k0 + ac];
        float4 b4 = *(const float4*)&Bw[(size_t)(k0 + bk) * 512 + col0 + bc];
        __syncthreads();
        As[ac + 0][ar] = a4.x; As[ac + 1][ar] = a4.y;
        As[ac + 2][ar] = a4.z; As[ac + 3][ar] = a4.w;
        *(float4*)&Bs[bk][bc] = b4;
        __syncthreads();
        #pragma unroll
        for (int kk = 0; kk < 16; ++kk) {
            float a[4], bb[4];
            #pragma unroll
            for (int i = 0; i < 4; ++i) a[i] = As[kk][(ty << 2) + i];
            #pragma unroll
            for (int j = 0; j < 4; ++j) bb[j] = Bs[kk][(tx << 2) + j];
            #pragma unroll
            for (int i = 0; i < 4; ++i)
                #pragma unroll
                for (int j = 0; j < 4; ++j)
                    acc[i][j] = fmaf(a[i], bb[j], acc[i][j]);
        }
    }
    #pragma unroll
    for (int i = 0; i < 4; ++i) {
        int row = row0 + (ty << 2) + i;
        int b = row >> 10, n = row & (NN - 1);
        float m = (n < slen[b]) ? 1.0f : 0.0f;
        int col = col0 + (tx << 2);
        float4 xv = *(const float4*)&X[(size_t)row * 512 + col];
        float4 o;
        o.x = (xv.x + acc[i][0] + bo[col + 0]) * m;
        o.y = (xv.y + acc[i][1] + bo[col + 1]) * m;
        o.z = (xv.z + acc[i][2] + bo[col + 2]) * m;
        o.w = (xv.w + acc[i][3] + bo[col + 3]) * m;
        *(float4*)&X[(size_t)row * 512 + col] = o;
    }
}

// ---------------------------------------------------------------- fused attention
// per (b, h, n-tile of 64): av[n,:] = sum_{m<=n} silu(q.k + posw[m-n+1023]) / N * v[m,:]
__global__ __launch_bounds__(256) void k_attn(const float* __restrict__ uvqk,
                                              const float* __restrict__ posw,
                                              float* __restrict__ av) {
    __shared__ float Qt[64][68];  // [d][i]
    __shared__ float Kt[64][68];  // [d][j]
    __shared__ float Vs[64][68];  // [j][d]
    __shared__ float Ps[64][68];  // [j][i]
    int nt = blockIdx.x, h = blockIdx.y, b = blockIdx.z;
    int n0 = nt << 6;
    int tid = threadIdx.x;
    int tx = tid & 15, ty = tid >> 4;
    int r = tid >> 4, c4 = (tid & 15) << 2;
    const float* base = uvqk + (size_t)b * NN * UVQK_C;
    const float* qb = base + 1024 + h * 64;
    const float* kb = base + 1536 + h * 64;
    const float* vb = base + 512 + h * 64;

    #pragma unroll
    for (int rr = 0; rr < 4; ++rr) {
        int row = (rr << 4) + r;
        float4 g = *(const float4*)&qb[(size_t)(n0 + row) * UVQK_C + c4];
        Qt[c4 + 0][row] = g.x; Qt[c4 + 1][row] = g.y;
        Qt[c4 + 2][row] = g.z; Qt[c4 + 3][row] = g.w;
    }
    float acc[4][4] = {};
    for (int mt = 0; mt <= nt; ++mt) {
        int m0 = mt << 6;
        __syncthreads();
        #pragma unroll
        for (int rr = 0; rr < 4; ++rr) {
            int row = (rr << 4) + r;
            float4 gk = *(const float4*)&kb[(size_t)(m0 + row) * UVQK_C + c4];
            Kt[c4 + 0][row] = gk.x; Kt[c4 + 1][row] = gk.y;
            Kt[c4 + 2][row] = gk.z; Kt[c4 + 3][row] = gk.w;
            float4 gv = *(const float4*)&vb[(size_t)(m0 + row) * UVQK_C + c4];
            *(float4*)&Vs[row][c4] = gv;
        }
        __syncthreads();
        float s[4][4] = {};
        for (int d = 0; d < 64; ++d) {
            float a[4], bb[4];
            #pragma unroll
            for (int i = 0; i < 4; ++i) a[i] = Qt[d][(ty << 2) + i];
            #pragma unroll
            for (int j = 0; j < 4; ++j) bb[j] = Kt[d][(tx << 2) + j];
            #pragma unroll
            for (int i = 0; i < 4; ++i)
                #pragma unroll
                for (int j = 0; j < 4; ++j)
                    s[i][j] = fmaf(a[i], bb[j], s[i][j]);
        }
        #pragma unroll
        for (int i = 0; i < 4; ++i) {
            int n = n0 + (ty << 2) + i;
            #pragma unroll
            for (int j = 0; j < 4; ++j) {
                int m = m0 + (tx << 2) + j;
                float val = s[i][j] + posw[m - n + (NN - 1)];
                float p = (m <= n) ? silu_f(val) * (1.0f / NN) : 0.0f;
                Ps[(tx << 2) + j][(ty << 2) + i] = p;
            }
        }
        __syncthreads();
        for (int j = 0; j < 64; ++j) {
            float p[4], v[4];
            #pragma unroll
            for (int i = 0; i < 4; ++i) p[i] = Ps[j][(ty << 2) + i];
            #pragma unroll
            for (int dd = 0; dd < 4; ++dd) v[dd] = Vs[j][(tx << 2) + dd];
            #pragma unroll
            for (int i = 0; i < 4; ++i)
                #pragma unroll
                for (int dd = 0; dd < 4; ++dd)
                    acc[i][dd] = fmaf(p[i], v[dd], acc[i][dd]);
        }
    }
    #pragma unroll
    for (int i = 0; i < 4; ++i) {
        int n = n0 + (ty << 2) + i;
        float4 o = make_float4(acc[i][0], acc[i][1], acc[i][2], acc[i][3]);
        *(float4*)&av[(size_t)(b * NN + n) * 512 + h * 64 + (tx << 2)] = o;
    }
}

// ---------------------------------------------------------------- final L2 norm
__global__ __launch_bounds__(256) void k_norm(float* __restrict__ X) {
    __shared__ float sbuf[4];
    int row = blockIdx.x;
    int c = threadIdx.x << 1;
    float2 v = *(const float2*)&X[(size_t)row * 512 + c];
    float ss = v.x * v.x + v.y * v.y;
    #pragma unroll
    for (int off = 1; off < 64; off <<= 1) ss += __shfl_xor(ss, off);
    if ((threadIdx.x & 63) == 0) sbuf[threadIdx.x >> 6] = ss;
    __syncthreads();
    ss = sbuf[0] + sbuf[1] + sbuf[2] + sbuf[3];
    float norm = sqrtf(ss);
    float sc = 1.0f / fmaxf(norm, 1e-6f);
    X[(size_t)row * 512 + c] = v.x * sc;
    X[(size_t)row * 512 + c + 1] = v.y * sc;
}

// ---------------------------------------------------------------- launch
extern "C" void kernel_launch(void* const* d_in, const int* in_sizes, int n_in,
                              void* d_out, int out_size, void* d_ws, size_t ws_size,
                              hipStream_t stream) {
    const float* seq   = (const float*)d_in[0];
    const int*   slen  = (const int*)d_in[1];
    const float* pos   = (const float*)d_in[2];
    const float* ln1g  = (const float*)d_in[3];
    const float* ln1b  = (const float*)d_in[4];
    const float* wuvqk = (const float*)d_in[5];
    const float* ln2g  = (const float*)d_in[6];
    const float* ln2b  = (const float*)d_in[7];
    const float* wo    = (const float*)d_in[8];
    const float* bo    = (const float*)d_in[9];
    const float* posw  = (const float*)d_in[10];

    float* x  = (float*)d_out;
    float* ws = (float*)d_ws;
    float* nx   = ws;                          // 4096*512
    float* av   = ws + (size_t)ROWS * 512;     // 4096*512
    float* uvqk = ws + (size_t)ROWS * 1024;    // 4096*2048

    k_init<<<ROWS, 128, 0, stream>>>(seq, pos, slen, x);
    for (int l = 0; l < NBL; ++l) {
        k_ln<<<ROWS, 256, 0, stream>>>(x, ln1g + l * 512, ln1b + l * 512, nx, nullptr);
        k_gemm_silu<<<dim3(UVQK_C / 64, ROWS / 64), 256, 0, stream>>>(
            nx, wuvqk + (size_t)l * 512 * UVQK_C, uvqk, UVQK_C, 512);
        k_attn<<<dim3(16, 8, 4), 256, 0, stream>>>(uvqk, posw + l * (2 * NN - 1), av);
        k_ln<<<ROWS, 256, 0, stream>>>(av, ln2g + l * 512, ln2b + l * 512, nx, uvqk);
        k_gemm_out<<<dim3(512 / 64, ROWS / 64), 256, 0, stream>>>(
            nx, wo + (size_t)l * 512 * 512, bo + l * 512, slen, x);
    }
    k_norm<<<ROWS, 256, 0, stream>>>(x);
}

// Round 2
// 332.181 us; speedup vs baseline: 3.8153x; 3.8153x over previous
//
#include <hip/hip_runtime.h>
#include <math.h>
#include <stdint.h>

#define BB 4
#define NN 1024
#define DD 512
#define HH 8
#define ROWS (BB * NN)   // 4096
#define NBL 4

typedef _Float16 h8 __attribute__((ext_vector_type(8)));
typedef _Float16 h4 __attribute__((ext_vector_type(4)));
typedef _Float16 h2 __attribute__((ext_vector_type(2)));
typedef float f4 __attribute__((ext_vector_type(4)));

__device__ __forceinline__ float fast_silu(float x) {
    // x * sigmoid(x); exp(-x) = exp2(-x*log2(e)); v_exp_f32 + v_rcp_f32
    float e = __builtin_amdgcn_exp2f(-1.4426950408889634f * x);
    return x * __builtin_amdgcn_rcpf(1.0f + e);
}

// async global->LDS, 16B per lane; LDS dest must be wave-uniform base
__device__ __forceinline__ void gl16(const void* gp, void* lp) {
    __builtin_amdgcn_global_load_lds(
        (const __attribute__((address_space(1))) uint32_t*)gp,
        (__attribute__((address_space(3))) uint32_t*)lp, 16, 0, 0);
}

// ---------------------------------------------------------------- transpose+fp16 convert
// src f32 [K][N] -> dst f16 [N][K], per blockIdx.z slab of K*N
__global__ __launch_bounds__(256) void k_transpose16(const float* __restrict__ src,
                                                     _Float16* __restrict__ dst,
                                                     int K, int N) {
    __shared__ _Float16 T[64][66];
    int n0 = blockIdx.x << 6, k0 = blockIdx.y << 6;
    size_t zo = (size_t)blockIdx.z * K * N;
    const float* s = src + zo;
    _Float16* d = dst + zo;
    int tx = threadIdx.x & 63, ty = threadIdx.x >> 6;
    #pragma unroll
    for (int q = 0; q < 16; ++q)
        T[(q << 2) + ty][tx] = (_Float16)s[(size_t)(k0 + (q << 2) + ty) * N + n0 + tx];
    __syncthreads();
    #pragma unroll
    for (int q = 0; q < 16; ++q)
        d[(size_t)(n0 + (q << 2) + ty) * K + k0 + tx] = T[tx][(q << 2) + ty];
}

// ---------------------------------------------------------------- init
__global__ __launch_bounds__(128) void k_init(const float* __restrict__ seq,
                                              const float* __restrict__ pos,
                                              const int* __restrict__ slen,
                                              float* __restrict__ x) {
    int row = blockIdx.x;
    int b = row >> 10, n = row & (NN - 1);
    float m = (n < slen[b]) ? 1.0f : 0.0f;
    int c = threadIdx.x << 2;
    float4 s4 = *(const float4*)&seq[(size_t)row * DD + c];
    float4 p4 = *(const float4*)&pos[(size_t)n * DD + c];
    const float SD = 22.627416997969522f;
    float4 o;
    o.x = (s4.x * SD + p4.x) * m;
    o.y = (s4.y * SD + p4.y) * m;
    o.z = (s4.z * SD + p4.z) * m;
    o.w = (s4.w * SD + p4.w) * m;
    *(float4*)&x[(size_t)row * DD + c] = o;
}

// ---------------------------------------------------------------- layernorm -> fp16
// O[row] = (LN(X[row])*g + b) [* U[row] fp16, stride 2048]
__global__ __launch_bounds__(256) void k_ln(const float* __restrict__ X,
                                            const float* __restrict__ g,
                                            const float* __restrict__ bt,
                                            _Float16* __restrict__ O,
                                            const _Float16* __restrict__ U) {
    __shared__ float sbuf[4];
    int row = blockIdx.x;
    int c = threadIdx.x << 1;
    float2 v = *(const float2*)&X[(size_t)row * 512 + c];

    float s = v.x + v.y;
    #pragma unroll
    for (int off = 1; off < 64; off <<= 1) s += __shfl_xor(s, off);
    if ((threadIdx.x & 63) == 0) sbuf[threadIdx.x >> 6] = s;
    __syncthreads();
    s = sbuf[0] + sbuf[1] + sbuf[2] + sbuf[3];
    float mu = s * (1.0f / 512.0f);
    float dx = v.x - mu, dy = v.y - mu;
    float ss = dx * dx + dy * dy;
    __syncthreads();
    #pragma unroll
    for (int off = 1; off < 64; off <<= 1) ss += __shfl_xor(ss, off);
    if ((threadIdx.x & 63) == 0) sbuf[threadIdx.x >> 6] = ss;
    __syncthreads();
    ss = sbuf[0] + sbuf[1] + sbuf[2] + sbuf[3];
    float rs = rsqrtf(ss * (1.0f / 512.0f) + 1e-6f);

    float o0 = dx * rs * g[c] + bt[c];
    float o1 = dy * rs * g[c + 1] + bt[c + 1];
    if (U) {
        o0 *= (float)U[(size_t)row * 2048 + c];
        o1 *= (float)U[(size_t)row * 2048 + c + 1];
    }
    h2 o;
    o[0] = (_Float16)o0; o[1] = (_Float16)o1;
    *(h2*)&O[(size_t)row * 512 + c] = o;
}

// ---------------------------------------------------------------- MFMA GEMM (fp16 in, f32 acc)
// C[4096 x Ncols] = A[4096 x K] @ B[K x Ncols], B given pre-transposed [Ncols][K]
// EPI 0: silu -> uvqk16 (u/q/k cols) + vT16 (v cols, transposed [b][h][d][n])
// EPI 1: X = (X + C + bo) * mask  (f32, in place)
template<int EPI>
__global__ __launch_bounds__(256) void k_gemm(const _Float16* __restrict__ A,
                                              const _Float16* __restrict__ Bm,
                                              int K, int Ncols,
                                              _Float16* __restrict__ Cu,
                                              _Float16* __restrict__ vT,
                                              const float* __restrict__ bo,
                                              const int* __restrict__ slen,
                                              float* __restrict__ Xio) {
    __shared__ _Float16 As[128 * 64];   // [row][64k] rows 128B, chunk-swizzled
    __shared__ _Float16 Bs[128 * 64];
    int tid = threadIdx.x;
    int w = tid >> 6, lane = tid & 63;
    int t = lane & 15, gq = lane >> 4;
    int row0 = blockIdx.y << 7, col0 = blockIdx.x << 7;

    f4 zero4 = {0.0f, 0.0f, 0.0f, 0.0f};
    f4 acc[4][4];
    #pragma unroll
    for (int i = 0; i < 4; ++i)
        #pragma unroll
        for (int j = 0; j < 4; ++j) acc[i][j] = zero4;

    int wr = (w >> 1) << 6, wc = (w & 1) << 6;

    for (int k0 = 0; k0 < K; k0 += 64) {
        __syncthreads();
        #pragma unroll
        for (int q = 0; q < 4; ++q) {
            int s = (w << 8) + (q << 6) + lane;
            int r = s >> 3, cs = (s & 7) ^ (r & 7);
            gl16(A + (size_t)(row0 + r) * K + k0 + (cs << 3),
                 (char*)As + (size_t)((w << 8) + (q << 6)) * 16);
            gl16(Bm + (size_t)(col0 + r) * K + k0 + (cs << 3),
                 (char*)Bs + (size_t)((w << 8) + (q << 6)) * 16);
        }
        __syncthreads();
        h8 af[4][2], bf[4][2];
        #pragma unroll
        for (int i = 0; i < 4; ++i) {
            int rl = wr + (i << 4) + t;
            #pragma unroll
            for (int ks = 0; ks < 2; ++ks)
                af[i][ks] = *(const h8*)((const char*)As + rl * 128 +
                                         (((gq + (ks << 2)) ^ (rl & 7)) << 4));
        }
        #pragma unroll
        for (int j = 0; j < 4; ++j) {
            int nl = wc + (j << 4) + t;
            #pragma unroll
            for (int ks = 0; ks < 2; ++ks)
                bf[j][ks] = *(const h8*)((const char*)Bs + nl * 128 +
                                         (((gq + (ks << 2)) ^ (nl & 7)) << 4));
        }
        #pragma unroll
        for (int i = 0; i < 4; ++i)
            #pragma unroll
            for (int j = 0; j < 4; ++j) {
                acc[i][j] = __builtin_amdgcn_mfma_f32_16x16x32_f16(af[i][0], bf[j][0], acc[i][j], 0, 0, 0);
                acc[i][j] = __builtin_amdgcn_mfma_f32_16x16x32_f16(af[i][1], bf[j][1], acc[i][j], 0, 0, 0);
            }
    }

    #pragma unroll
    for (int i = 0; i < 4; ++i) {
        #pragma unroll
        for (int j = 0; j < 4; ++j) {
            int colf = col0 + wc + (j << 4) + t;
            int rowb = row0 + wr + (i << 4) + (gq << 2);
            if (EPI == 0) {
                if (colf >= 512 && colf < 1024) {
                    int b = rowb >> 10;
                    int hh = (colf - 512) >> 6, dd = (colf - 512) & 63;
                    h4 pk;
                    #pragma unroll
                    for (int rr = 0; rr < 4; ++rr) pk[rr] = (_Float16)fast_silu(acc[i][j][rr]);
                    size_t off = ((size_t)((b << 3) + hh) * 64 + dd) * 1024 + (rowb & 1023);
                    *(h4*)&vT[off] = pk;
                } else {
                    #pragma unroll
                    for (int rr = 0; rr < 4; ++rr)
                        Cu[(size_t)(rowb + rr) * 2048 + colf] = (_Float16)fast_silu(acc[i][j][rr]);
                }
            } else {
                int b = rowb >> 10;
                #pragma unroll
                for (int rr = 0; rr < 4; ++rr) {
                    int row = rowb + rr;
                    float m = ((row & 1023) < slen[b]) ? 1.0f : 0.0f;
                    size_t ix = (size_t)row * 512 + colf;
                    Xio[ix] = (Xio[ix] + acc[i][j][rr] + bo[colf]) * m;
                }
            }
        }
    }
}

// ---------------------------------------------------------------- fused attention (MFMA)
// per (b, h, nt): av[n,:] = (1/N) * sum_{m<=n} silu(q.k + posw[m-n+1023]) * v[m,:]
__global__ __launch_bounds__(256) void k_attn(const _Float16* __restrict__ uvqk,
                                              const _Float16* __restrict__ vT,
                                              const float* __restrict__ posw,
                                              float* __restrict__ av) {
    __shared__ _Float16 Ks[64 * 64];   // [m][d] swizzled (also Q staging)
    __shared__ _Float16 Vs[64 * 64];   // [d][m] swizzled
    __shared__ _Float16 Ps[64 * 72];   // [n][m], row stride 144B
    __shared__ float pw[128];
    int tid = threadIdx.x;
    int w = tid >> 6, lane = tid & 63;
    int t = lane & 15, gq = lane >> 4;
    int b = blockIdx.z, h = blockIdx.y;
    int nt = (b >= 2) ? (15 - (int)blockIdx.x) : (int)blockIdx.x;  // pair heavy+light tiles
    int n0 = nt << 6;

    const _Float16* qbase = uvqk + (size_t)b * NN * 2048 + 1024 + h * 64;
    const _Float16* kbase = uvqk + (size_t)b * NN * 2048 + 1536 + h * 64;
    const _Float16* vbase = vT + (size_t)((b << 3) + h) * 64 * 1024;

    // stage Q (rows n0..n0+63) into Ks, read A-frags to regs
    #pragma unroll
    for (int q = 0; q < 2; ++q) {
        int s = (((w << 1) + q) << 6) + lane;
        int r = s >> 3, cs = (s & 7) ^ (r & 7);
        gl16(qbase + (size_t)(n0 + r) * 2048 + (cs << 3),
             (char*)Ks + (size_t)(((w << 1) + q) << 6) * 16);
    }
    __syncthreads();
    h8 aq[2];
    {
        int rl = (w << 4) + t;
        #pragma unroll
        for (int ks = 0; ks < 2; ++ks)
            aq[ks] = *(const h8*)((const char*)Ks + rl * 128 +
                                  (((gq + (ks << 2)) ^ (rl & 7)) << 4));
    }

    f4 zero4 = {0.0f, 0.0f, 0.0f, 0.0f};
    f4 avacc[4];
    #pragma unroll
    for (int j = 0; j < 4; ++j) avacc[j] = zero4;

    for (int mt = 0; mt <= nt; ++mt) {
        int m0 = mt << 6;
        __syncthreads();   // prior reads of Ks/Vs (and Q frags) drained
        #pragma unroll
        for (int q = 0; q < 2; ++q) {
            int s = (((w << 1) + q) << 6) + lane;
            int r = s >> 3, cs = (s & 7) ^ (r & 7);
            gl16(kbase + (size_t)(m0 + r) * 2048 + (cs << 3),
                 (char*)Ks + (size_t)(((w << 1) + q) << 6) * 16);
            gl16(vbase + (size_t)r * 1024 + m0 + (cs << 3),
                 (char*)Vs + (size_t)(((w << 1) + q) << 6) * 16);
        }
        if (tid < 128) pw[tid] = posw[m0 - n0 + tid + 960];
        __syncthreads();

        // S = Q K^T (+bias, silu, causal) per wave: 16 rows x 64 cols
        f4 sacc[4];
        #pragma unroll
        for (int jt = 0; jt < 4; ++jt) sacc[jt] = zero4;
        #pragma unroll
        for (int jt = 0; jt < 4; ++jt) {
            int ml = (jt << 4) + t;
            #pragma unroll
            for (int ks = 0; ks < 2; ++ks) {
                h8 bk = *(const h8*)((const char*)Ks + ml * 128 +
                                     (((gq + (ks << 2)) ^ (ml & 7)) << 4));
                sacc[jt] = __builtin_amdgcn_mfma_f32_16x16x32_f16(aq[ks], bk, sacc[jt], 0, 0, 0);
            }
        }
        // P = silu(S + bias), causal; store fp16 WITHOUT 1/N (fp16 denormal safety)
        #pragma unroll
        for (int jt = 0; jt < 4; ++jt) {
            int ml = (jt << 4) + t;
            #pragma unroll
            for (int rr = 0; rr < 4; ++rr) {
                int nl = (w << 4) + (gq << 2) + rr;
                float sval = sacc[jt][rr] + pw[ml - nl + 63];
                float p = ((m0 + ml) <= (n0 + nl)) ? fast_silu(sval) : 0.0f;
                Ps[nl * 72 + ml] = (_Float16)p;
            }
        }
        asm volatile("s_waitcnt lgkmcnt(0)" ::: "memory");  // Ps writes visible (per-wave region)
        // AV += P @ V
        #pragma unroll
        for (int ks = 0; ks < 2; ++ks) {
            h8 pa = *(const h8*)((const char*)Ps + ((w << 4) + t) * 144 + (ks << 6) + (gq << 4));
            #pragma unroll
            for (int jt = 0; jt < 4; ++jt) {
                int dl = (jt << 4) + t;
                h8 bv = *(const h8*)((const char*)Vs + dl * 128 +
                                     (((gq + (ks << 2)) ^ (dl & 7)) << 4));
                avacc[jt] = __builtin_amdgcn_mfma_f32_16x16x32_f16(pa, bv, avacc[jt], 0, 0, 0);
            }
        }
    }

    #pragma unroll
    for (int jt = 0; jt < 4; ++jt) {
        #pragma unroll
        for (int rr = 0; rr < 4; ++rr) {
            int n = n0 + (w << 4) + (gq << 2) + rr;
            int d = (jt << 4) + t;
            av[(size_t)(b * NN + n) * 512 + h * 64 + d] = avacc[jt][rr] * (1.0f / 1024.0f);
        }
    }
}

// ---------------------------------------------------------------- final L2 norm
__global__ __launch_bounds__(256) void k_norm(float* __restrict__ X) {
    __shared__ float sbuf[4];
    int row = blockIdx.x;
    int c = threadIdx.x << 1;
    float2 v = *(const float2*)&X[(size_t)row * 512 + c];
    float ss = v.x * v.x + v.y * v.y;
    #pragma unroll
    for (int off = 1; off < 64; off <<= 1) ss += __shfl_xor(ss, off);
    if ((threadIdx.x & 63) == 0) sbuf[threadIdx.x >> 6] = ss;
    __syncthreads();
    ss = sbuf[0] + sbuf[1] + sbuf[2] + sbuf[3];
    float norm = sqrtf(ss);
    float sc = 1.0f / fmaxf(norm, 1e-6f);
    X[(size_t)row * 512 + c] = v.x * sc;
    X[(size_t)row * 512 + c + 1] = v.y * sc;
}

// ---------------------------------------------------------------- launch
extern "C" void kernel_launch(void* const* d_in, const int* in_sizes, int n_in,
                              void* d_out, int out_size, void* d_ws, size_t ws_size,
                              hipStream_t stream) {
    const float* seq   = (const float*)d_in[0];
    const int*   slen  = (const int*)d_in[1];
    const float* pos   = (const float*)d_in[2];
    const float* ln1g  = (const float*)d_in[3];
    const float* ln1b  = (const float*)d_in[4];
    const float* wuvqk = (const float*)d_in[5];
    const float* ln2g  = (const float*)d_in[6];
    const float* ln2b  = (const float*)d_in[7];
    const float* wo    = (const float*)d_in[8];
    const float* bo    = (const float*)d_in[9];
    const float* posw  = (const float*)d_in[10];

    float* x = (float*)d_out;
    char* W = (char*)d_ws;
    _Float16* nx16   = (_Float16*)(W);                       // 4 MiB
    _Float16* oin16  = (_Float16*)(W + (4u << 20));          // 4 MiB
    _Float16* uvqk16 = (_Float16*)(W + (8u << 20));          // 16 MiB (v cols unused)
    _Float16* vT16   = (_Float16*)(W + (24u << 20));         // 4 MiB [b][h][d][n]
    float*    av     = (float*)   (W + (28u << 20));         // 8 MiB
    _Float16* wuT16  = (_Float16*)(W + (36u << 20));         // 8 MiB [l][2048][512]
    _Float16* woT16  = (_Float16*)(W + (44u << 20));         // 2 MiB [l][512][512]

    k_transpose16<<<dim3(32, 8, NBL), 256, 0, stream>>>(wuvqk, wuT16, 512, 2048);
    k_transpose16<<<dim3(8, 8, NBL), 256, 0, stream>>>(wo, woT16, 512, 512);
    k_init<<<ROWS, 128, 0, stream>>>(seq, pos, slen, x);
    for (int l = 0; l < NBL; ++l) {
        k_ln<<<ROWS, 256, 0, stream>>>(x, ln1g + l * 512, ln1b + l * 512, nx16, nullptr);
        k_gemm<0><<<dim3(16, 32), 256, 0, stream>>>(nx16, wuT16 + (size_t)l * 2048 * 512, 512, 2048,
                                                    uvqk16, vT16, nullptr, nullptr, nullptr);
        k_attn<<<dim3(16, 8, NBL), 256, 0, stream>>>(uvqk16, vT16, posw + l * (2 * NN - 1), av);
        k_ln<<<ROWS, 256, 0, stream>>>(av, ln2g + l * 512, ln2b + l * 512, oin16, uvqk16);
        k_gemm<1><<<dim3(4, 32), 256, 0, stream>>>(oin16, woT16 + (size_t)l * 512 * 512, 512, 512,
                                                   nullptr, nullptr, bo + l * 512, slen, x);
    }
    k_norm<<<ROWS, 256, 0, stream>>>(x);
}

// Round 3
// 263.174 us; speedup vs baseline: 4.8157x; 1.2622x over previous
//
#include <hip/hip_runtime.h>
#include <math.h>
#include <stdint.h>

#define BB 4
#define NN 1024
#define DD 512
#define HH 8
#define ROWS (BB * NN)   // 4096
#define NBL 4

typedef _Float16 h8 __attribute__((ext_vector_type(8)));
typedef _Float16 h4 __attribute__((ext_vector_type(4)));
typedef _Float16 h2 __attribute__((ext_vector_type(2)));
typedef float f4 __attribute__((ext_vector_type(4)));

__device__ __forceinline__ float fast_silu(float x) {
    float e = __builtin_amdgcn_exp2f(-1.4426950408889634f * x);
    return x * __builtin_amdgcn_rcpf(1.0f + e);
}

// async global->LDS, 16B/lane; LDS dest = wave-uniform base + lane*16
__device__ __forceinline__ void gl16(const void* gp, void* lp) {
    __builtin_amdgcn_global_load_lds(
        (const __attribute__((address_space(1))) uint32_t*)gp,
        (__attribute__((address_space(3))) uint32_t*)lp, 16, 0, 0);
}

// ---------------------------------------------------------------- transpose+fp16 convert
__global__ __launch_bounds__(256) void k_transpose16(const float* __restrict__ src,
                                                     _Float16* __restrict__ dst,
                                                     int K, int N) {
    __shared__ _Float16 T[64][66];
    int n0 = blockIdx.x << 6, k0 = blockIdx.y << 6;
    size_t zo = (size_t)blockIdx.z * K * N;
    const float* s = src + zo;
    _Float16* d = dst + zo;
    int tx = threadIdx.x & 63, ty = threadIdx.x >> 6;
    #pragma unroll
    for (int q = 0; q < 16; ++q)
        T[(q << 2) + ty][tx] = (_Float16)s[(size_t)(k0 + (q << 2) + ty) * N + n0 + tx];
    __syncthreads();
    #pragma unroll
    for (int q = 0; q < 16; ++q)
        d[(size_t)(n0 + (q << 2) + ty) * K + k0 + tx] = T[tx][(q << 2) + ty];
}

// ---------------------------------------------------------------- init
__global__ __launch_bounds__(128) void k_init(const float* __restrict__ seq,
                                              const float* __restrict__ pos,
                                              const int* __restrict__ slen,
                                              float* __restrict__ x) {
    int row = blockIdx.x;
    int b = row >> 10, n = row & (NN - 1);
    float m = (n < slen[b]) ? 1.0f : 0.0f;
    int c = threadIdx.x << 2;
    float4 s4 = *(const float4*)&seq[(size_t)row * DD + c];
    float4 p4 = *(const float4*)&pos[(size_t)n * DD + c];
    const float SD = 22.627416997969522f;
    float4 o;
    o.x = (s4.x * SD + p4.x) * m;
    o.y = (s4.y * SD + p4.y) * m;
    o.z = (s4.z * SD + p4.z) * m;
    o.w = (s4.w * SD + p4.w) * m;
    *(float4*)&x[(size_t)row * DD + c] = o;
}

// ---------------------------------------------------------------- layernorm -> fp16
// rows with (row&1023)>=512 add X2 (attn split-m partial) before normalizing
__global__ __launch_bounds__(256) void k_ln(const float* __restrict__ X,
                                            const float* __restrict__ X2,
                                            const float* __restrict__ g,
                                            const float* __restrict__ bt,
                                            _Float16* __restrict__ O,
                                            const _Float16* __restrict__ U) {
    __shared__ float sbuf[4];
    int row = blockIdx.x;
    int c = threadIdx.x << 1;
    float2 v = *(const float2*)&X[(size_t)row * 512 + c];
    if (X2 && (row & 1023) >= 512) {
        float2 v2 = *(const float2*)&X2[(size_t)row * 512 + c];
        v.x += v2.x; v.y += v2.y;
    }

    float s = v.x + v.y;
    #pragma unroll
    for (int off = 1; off < 64; off <<= 1) s += __shfl_xor(s, off);
    if ((threadIdx.x & 63) == 0) sbuf[threadIdx.x >> 6] = s;
    __syncthreads();
    s = sbuf[0] + sbuf[1] + sbuf[2] + sbuf[3];
    float mu = s * (1.0f / 512.0f);
    float dx = v.x - mu, dy = v.y - mu;
    float ss = dx * dx + dy * dy;
    __syncthreads();
    #pragma unroll
    for (int off = 1; off < 64; off <<= 1) ss += __shfl_xor(ss, off);
    if ((threadIdx.x & 63) == 0) sbuf[threadIdx.x >> 6] = ss;
    __syncthreads();
    ss = sbuf[0] + sbuf[1] + sbuf[2] + sbuf[3];
    float rs = rsqrtf(ss * (1.0f / 512.0f) + 1e-6f);

    float o0 = dx * rs * g[c] + bt[c];
    float o1 = dy * rs * g[c + 1] + bt[c + 1];
    if (U) {
        o0 *= (float)U[(size_t)row * 2048 + c];
        o1 *= (float)U[(size_t)row * 2048 + c + 1];
    }
    h2 o;
    o[0] = (_Float16)o0; o[1] = (_Float16)o1;
    *(h2*)&O[(size_t)row * 512 + c] = o;
}

// ---------------------------------------------------------------- MFMA GEMM (fp16 in, f32 acc)
// C[ROWS x Ncols] = A[ROWS x K] @ B (pre-transposed [Ncols][K]); dbuf + prefetch
template<int EPI, int BM, int BN>
__global__ __launch_bounds__(256) void k_gemm(const _Float16* __restrict__ A,
                                              const _Float16* __restrict__ Bm,
                                              int K, int Ncols,
                                              _Float16* __restrict__ Cu,
                                              _Float16* __restrict__ vT,
                                              const float* __restrict__ bo,
                                              const int* __restrict__ slen,
                                              float* __restrict__ Xio) {
    constexpr int WR = BM / 32;   // 16-row frags per wave
    constexpr int WC = BN / 32;
    __shared__ _Float16 As[2][BM * 64];
    __shared__ _Float16 Bs[2][BN * 64];
    int tid = threadIdx.x;
    int w = tid >> 6, lane = tid & 63;
    int t = lane & 15, gq = lane >> 4;
    int row0 = blockIdx.y * BM, col0 = blockIdx.x * BN;
    int wr = (w >> 1) * (BM / 2), wc = (w & 1) * (BN / 2);

    f4 zero4 = {0.0f, 0.0f, 0.0f, 0.0f};
    f4 acc[WR][WC];
    #pragma unroll
    for (int i = 0; i < WR; ++i)
        #pragma unroll
        for (int j = 0; j < WC; ++j) acc[i][j] = zero4;

    auto stage = [&](int buf, int k0) {
        #pragma unroll
        for (int q = 0; q < BM / 32; ++q) {
            int s = ((q << 2) + w) * 64 + lane;
            int r = s >> 3, cs = (s & 7) ^ (r & 7);
            gl16(A + (size_t)(row0 + r) * K + k0 + (cs << 3),
                 (char*)&As[buf][0] + (size_t)((q << 2) + w) * 1024);
        }
        #pragma unroll
        for (int q = 0; q < BN / 32; ++q) {
            int s = ((q << 2) + w) * 64 + lane;
            int r = s >> 3, cs = (s & 7) ^ (r & 7);
            gl16(Bm + (size_t)(col0 + r) * K + k0 + (cs << 3),
                 (char*)&Bs[buf][0] + (size_t)((q << 2) + w) * 1024);
        }
    };

    stage(0, 0);
    int cur = 0;
    for (int k0 = 0; k0 < K; k0 += 64) {
        __syncthreads();                    // stage(cur) landed (vmcnt drained here)
        if (k0 + 64 < K) stage(cur ^ 1, k0 + 64);
        h8 af[WR][2], bf[WC][2];
        #pragma unroll
        for (int i = 0; i < WR; ++i) {
            int rl = wr + (i << 4) + t;
            #pragma unroll
            for (int ks = 0; ks < 2; ++ks)
                af[i][ks] = *(const h8*)((const char*)&As[cur][0] + rl * 128 +
                                         (((gq + (ks << 2)) ^ (rl & 7)) << 4));
        }
        #pragma unroll
        for (int j = 0; j < WC; ++j) {
            int nl = wc + (j << 4) + t;
            #pragma unroll
            for (int ks = 0; ks < 2; ++ks)
                bf[j][ks] = *(const h8*)((const char*)&Bs[cur][0] + nl * 128 +
                                         (((gq + (ks << 2)) ^ (nl & 7)) << 4));
        }
        #pragma unroll
        for (int i = 0; i < WR; ++i)
            #pragma unroll
            for (int j = 0; j < WC; ++j) {
                acc[i][j] = __builtin_amdgcn_mfma_f32_16x16x32_f16(af[i][0], bf[j][0], acc[i][j], 0, 0, 0);
                acc[i][j] = __builtin_amdgcn_mfma_f32_16x16x32_f16(af[i][1], bf[j][1], acc[i][j], 0, 0, 0);
            }
        cur ^= 1;
    }

    #pragma unroll
    for (int i = 0; i < WR; ++i) {
        #pragma unroll
        for (int j = 0; j < WC; ++j) {
            int colf = col0 + wc + (j << 4) + t;
            int rowb = row0 + wr + (i << 4) + (gq << 2);
            if (EPI == 0) {
                if (colf >= 512 && colf < 1024) {
                    int b = rowb >> 10;
                    int hh = (colf - 512) >> 6, dd = (colf - 512) & 63;
                    h4 pk;
                    #pragma unroll
                    for (int rr = 0; rr < 4; ++rr) pk[rr] = (_Float16)fast_silu(acc[i][j][rr]);
                    size_t off = ((size_t)((b << 3) + hh) * 64 + dd) * 1024 + (rowb & 1023);
                    *(h4*)&vT[off] = pk;
                } else {
                    #pragma unroll
                    for (int rr = 0; rr < 4; ++rr)
                        Cu[(size_t)(rowb + rr) * 2048 + colf] = (_Float16)fast_silu(acc[i][j][rr]);
                }
            } else {
                int b = rowb >> 10;
                #pragma unroll
                for (int rr = 0; rr < 4; ++rr) {
                    int row = rowb + rr;
                    float m = ((row & 1023) < slen[b]) ? 1.0f : 0.0f;
                    size_t ix = (size_t)row * 512 + colf;
                    Xio[ix] = (Xio[ix] + acc[i][j][rr] + bo[colf]) * m;
                }
            }
        }
    }
}

// ---------------------------------------------------------------- fused attention (MFMA)
// grid x in [0,24): x<8 -> nt=x full range -> av0; x>=8 -> nt=8+(x-8)/2,
// half (x-8)&1: half0 m-tiles [0,c0)->av0, half1 [c0,nt]->av1 (summed in k_ln)
__global__ __launch_bounds__(256) void k_attn(const _Float16* __restrict__ uvqk,
                                              const _Float16* __restrict__ vT,
                                              const float* __restrict__ posw,
                                              float* __restrict__ av0,
                                              float* __restrict__ av1) {
    __shared__ _Float16 Ks[2][64 * 64];
    __shared__ _Float16 Vs[2][64 * 64];
    __shared__ _Float16 Ps[64 * 72];
    __shared__ float pw[2][128];
    int tid = threadIdx.x;
    int w = tid >> 6, lane = tid & 63;
    int t = lane & 15, gq = lane >> 4;
    int b = blockIdx.z, h = blockIdx.y, x = blockIdx.x;

    int nt, mlo, mhi;
    float* avout;
    if (x < 8) { nt = x; mlo = 0; mhi = nt; avout = av0; }
    else {
        int p = x - 8;
        nt = 8 + (p >> 1);
        int c0 = (nt + 2) >> 1;
        if (p & 1) { mlo = c0; mhi = nt; avout = av1; }
        else       { mlo = 0;  mhi = c0 - 1; avout = av0; }
    }
    int n0 = nt << 6;

    const _Float16* qbase = uvqk + (size_t)b * NN * 2048 + 1024 + h * 64;
    const _Float16* kbase = uvqk + (size_t)b * NN * 2048 + 1536 + h * 64;
    const _Float16* vbase = vT + (size_t)((b << 3) + h) * 64 * 1024;

    auto stageKV = [&](int buf, int mt) {
        int m0 = mt << 6;
        #pragma unroll
        for (int q = 0; q < 2; ++q) {
            int s = (((w << 1) + q) << 6) + lane;
            int r = s >> 3, cs = (s & 7) ^ (r & 7);
            gl16(kbase + (size_t)(m0 + r) * 2048 + (cs << 3),
                 (char*)&Ks[buf][0] + (size_t)(((w << 1) + q) << 6) * 16);
            gl16(vbase + (size_t)r * 1024 + m0 + (cs << 3),
                 (char*)&Vs[buf][0] + (size_t)(((w << 1) + q) << 6) * 16);
        }
    };

    // stage Q into Ks[1] (scratch), K/V(mlo) into buf 0, pw(mlo) into pw[0]
    #pragma unroll
    for (int q = 0; q < 2; ++q) {
        int s = (((w << 1) + q) << 6) + lane;
        int r = s >> 3, cs = (s & 7) ^ (r & 7);
        gl16(qbase + (size_t)(n0 + r) * 2048 + (cs << 3),
             (char*)&Ks[1][0] + (size_t)(((w << 1) + q) << 6) * 16);
    }
    stageKV(0, mlo);
    if (tid < 128) pw[0][tid] = posw[(mlo << 6) - n0 + tid + 960];
    __syncthreads();

    h8 aq[2];
    {
        int rl = (w << 4) + t;
        #pragma unroll
        for (int ks = 0; ks < 2; ++ks)
            aq[ks] = *(const h8*)((const char*)&Ks[1][0] + rl * 128 +
                                  (((gq + (ks << 2)) ^ (rl & 7)) << 4));
    }
    asm volatile("s_waitcnt lgkmcnt(0)" ::: "memory");  // aq in regs before Ks[1] reuse
    __builtin_amdgcn_sched_barrier(0);

    f4 zero4 = {0.0f, 0.0f, 0.0f, 0.0f};
    f4 avacc[4];
    #pragma unroll
    for (int j = 0; j < 4; ++j) avacc[j] = zero4;

    int cur = 0;
    for (int mt = mlo; mt <= mhi; ++mt) {
        int m0 = mt << 6;
        if (mt < mhi) {                      // prefetch next tile into other buffer
            stageKV(cur ^ 1, mt + 1);
            if (tid < 128) pw[cur ^ 1][tid] = posw[((mt + 1) << 6) - n0 + tid + 960];
        }
        // S = Q K^T
        f4 sacc[4];
        #pragma unroll
        for (int jt = 0; jt < 4; ++jt) sacc[jt] = zero4;
        #pragma unroll
        for (int jt = 0; jt < 4; ++jt) {
            int ml = (jt << 4) + t;
            #pragma unroll
            for (int ks = 0; ks < 2; ++ks) {
                h8 bk = *(const h8*)((const char*)&Ks[cur][0] + ml * 128 +
                                     (((gq + (ks << 2)) ^ (ml & 7)) << 4));
                sacc[jt] = __builtin_amdgcn_mfma_f32_16x16x32_f16(aq[ks], bk, sacc[jt], 0, 0, 0);
            }
        }
        // P = silu(S + bias) with causal mask; fp16 without 1/N
        #pragma unroll
        for (int jt = 0; jt < 4; ++jt) {
            int ml = (jt << 4) + t;
            #pragma unroll
            for (int rr = 0; rr < 4; ++rr) {
                int nl = (w << 4) + (gq << 2) + rr;
                float sval = sacc[jt][rr] + pw[cur][ml - nl + 63];
                float p = ((m0 + ml) <= (n0 + nl)) ? fast_silu(sval) : 0.0f;
                Ps[nl * 72 + ml] = (_Float16)p;
            }
        }
        asm volatile("s_waitcnt lgkmcnt(0)" ::: "memory");  // per-wave Ps stripe visible
        // AV += P @ V
        #pragma unroll
        for (int ks = 0; ks < 2; ++ks) {
            h8 pa = *(const h8*)((const char*)Ps + ((w << 4) + t) * 144 + (ks << 6) + (gq << 4));
            #pragma unroll
            for (int jt = 0; jt < 4; ++jt) {
                int dl = (jt << 4) + t;
                h8 bv = *(const h8*)((const char*)&Vs[cur][0] + dl * 128 +
                                     (((gq + (ks << 2)) ^ (dl & 7)) << 4));
                avacc[jt] = __builtin_amdgcn_mfma_f32_16x16x32_f16(pa, bv, avacc[jt], 0, 0, 0);
            }
        }
        __syncthreads();                     // prefetch landed; reads of cur done
        cur ^= 1;
    }

    #pragma unroll
    for (int jt = 0; jt < 4; ++jt) {
        #pragma unroll
        for (int rr = 0; rr < 4; ++rr) {
            int n = n0 + (w << 4) + (gq << 2) + rr;
            int d = (jt << 4) + t;
            avout[(size_t)(b * NN + n) * 512 + h * 64 + d] = avacc[jt][rr] * (1.0f / 1024.0f);
        }
    }
}

// ---------------------------------------------------------------- final L2 norm
__global__ __launch_bounds__(256) void k_norm(float* __restrict__ X) {
    __shared__ float sbuf[4];
    int row = blockIdx.x;
    int c = threadIdx.x << 1;
    float2 v = *(const float2*)&X[(size_t)row * 512 + c];
    float ss = v.x * v.x + v.y * v.y;
    #pragma unroll
    for (int off = 1; off < 64; off <<= 1) ss += __shfl_xor(ss, off);
    if ((threadIdx.x & 63) == 0) sbuf[threadIdx.x >> 6] = ss;
    __syncthreads();
    ss = sbuf[0] + sbuf[1] + sbuf[2] + sbuf[3];
    float norm = sqrtf(ss);
    float sc = 1.0f / fmaxf(norm, 1e-6f);
    X[(size_t)row * 512 + c] = v.x * sc;
    X[(size_t)row * 512 + c + 1] = v.y * sc;
}

// ---------------------------------------------------------------- launch
extern "C" void kernel_launch(void* const* d_in, const int* in_sizes, int n_in,
                              void* d_out, int out_size, void* d_ws, size_t ws_size,
                              hipStream_t stream) {
    const float* seq   = (const float*)d_in[0];
    const int*   slen  = (const int*)d_in[1];
    const float* pos   = (const float*)d_in[2];
    const float* ln1g  = (const float*)d_in[3];
    const float* ln1b  = (const float*)d_in[4];
    const float* wuvqk = (const float*)d_in[5];
    const float* ln2g  = (const float*)d_in[6];
    const float* ln2b  = (const float*)d_in[7];
    const float* wo    = (const float*)d_in[8];
    const float* bo    = (const float*)d_in[9];
    const float* posw  = (const float*)d_in[10];

    float* x = (float*)d_out;
    char* W = (char*)d_ws;
    _Float16* nx16   = (_Float16*)(W);                       // 4 MiB
    _Float16* oin16  = (_Float16*)(W + (4u << 20));          // 4 MiB
    _Float16* uvqk16 = (_Float16*)(W + (8u << 20));          // 16 MiB
    _Float16* vT16   = (_Float16*)(W + (24u << 20));         // 4 MiB [b][h][d][n]
    float*    av0    = (float*)   (W + (28u << 20));         // 8 MiB
    float*    av1    = (float*)   (W + (36u << 20));         // 8 MiB
    _Float16* wuT16  = (_Float16*)(W + (44u << 20));         // 8 MiB [l][2048][512]
    _Float16* woT16  = (_Float16*)(W + (52u << 20));         // 2 MiB [l][512][512]

    k_transpose16<<<dim3(32, 8, NBL), 256, 0, stream>>>(wuvqk, wuT16, 512, 2048);
    k_transpose16<<<dim3(8, 8, NBL), 256, 0, stream>>>(wo, woT16, 512, 512);
    k_init<<<ROWS, 128, 0, stream>>>(seq, pos, slen, x);
    for (int l = 0; l < NBL; ++l) {
        k_ln<<<ROWS, 256, 0, stream>>>(x, nullptr, ln1g + l * 512, ln1b + l * 512, nx16, nullptr);
        k_gemm<0, 128, 128><<<dim3(16, 32), 256, 0, stream>>>(
            nx16, wuT16 + (size_t)l * 2048 * 512, 512, 2048, uvqk16, vT16, nullptr, nullptr, nullptr);
        k_attn<<<dim3(24, 8, NBL), 256, 0, stream>>>(uvqk16, vT16, posw + l * (2 * NN - 1), av0, av1);
        k_ln<<<ROWS, 256, 0, stream>>>(av0, av1, ln2g + l * 512, ln2b + l * 512, oin16, uvqk16);
        k_gemm<1, 64, 64><<<dim3(8, 64), 256, 0, stream>>>(
            oin16, woT16 + (size_t)l * 512 * 512, 512, 512, nullptr, nullptr, bo + l * 512, slen, x);
    }
    k_norm<<<ROWS, 256, 0, stream>>>(x);
}

// Round 4
// 254.174 us; speedup vs baseline: 4.9862x; 1.0354x over previous
//
#include <hip/hip_runtime.h>
#include <math.h>
#include <stdint.h>

#define BB 4
#define NN 1024
#define DD 512
#define HH 8
#define ROWS (BB * NN)   // 4096
#define NBL 4

typedef _Float16 h8 __attribute__((ext_vector_type(8)));
typedef _Float16 h4 __attribute__((ext_vector_type(4)));
typedef _Float16 h2 __attribute__((ext_vector_type(2)));
typedef float f4 __attribute__((ext_vector_type(4)));

__device__ __forceinline__ float fast_silu(float x) {
    float e = __builtin_amdgcn_exp2f(-1.4426950408889634f * x);
    return x * __builtin_amdgcn_rcpf(1.0f + e);
}

// async global->LDS, 16B/lane; LDS dest = wave-uniform base + lane*16
__device__ __forceinline__ void gl16(const void* gp, void* lp) {
    __builtin_amdgcn_global_load_lds(
        (const __attribute__((address_space(1))) uint32_t*)gp,
        (__attribute__((address_space(3))) uint32_t*)lp, 16, 0, 0);
}

// ---------------------------------------------------------------- transpose+fp16 convert
__global__ __launch_bounds__(256) void k_transpose16(const float* __restrict__ src,
                                                     _Float16* __restrict__ dst,
                                                     int K, int N) {
    __shared__ _Float16 T[64][66];
    int n0 = blockIdx.x << 6, k0 = blockIdx.y << 6;
    size_t zo = (size_t)blockIdx.z * K * N;
    const float* s = src + zo;
    _Float16* d = dst + zo;
    int tx = threadIdx.x & 63, ty = threadIdx.x >> 6;
    #pragma unroll
    for (int q = 0; q < 16; ++q)
        T[(q << 2) + ty][tx] = (_Float16)s[(size_t)(k0 + (q << 2) + ty) * N + n0 + tx];
    __syncthreads();
    #pragma unroll
    for (int q = 0; q < 16; ++q)
        d[(size_t)(n0 + (q << 2) + ty) * K + k0 + tx] = T[tx][(q << 2) + ty];
}

// ---------------------------------------------------------------- layernorm -> fp16
// INIT=1: v = (seq*sqrt(D)+pos)*mask computed on the fly, written to Xw, then LN'd.
// X2 (attn split-m partial) added for rows with (row&1023)>=512. U: *u multiply.
template<int INIT>
__global__ __launch_bounds__(256) void k_ln(const float* __restrict__ X,
                                            const float* __restrict__ X2,
                                            const float* __restrict__ seq,
                                            const float* __restrict__ pos,
                                            const int* __restrict__ slen,
                                            const float* __restrict__ g,
                                            const float* __restrict__ bt,
                                            _Float16* __restrict__ O,
                                            const _Float16* __restrict__ U,
                                            float* __restrict__ Xw) {
    __shared__ float sbuf[4];
    int row = blockIdx.x;
    int c = threadIdx.x << 1;
    float2 v;
    if (INIT) {
        int b = row >> 10, n = row & (NN - 1);
        float m = (n < slen[b]) ? 1.0f : 0.0f;
        float2 s2 = *(const float2*)&seq[(size_t)row * 512 + c];
        float2 p2 = *(const float2*)&pos[(size_t)n * 512 + c];
        const float SD = 22.627416997969522f;
        v.x = (s2.x * SD + p2.x) * m;
        v.y = (s2.y * SD + p2.y) * m;
        *(float2*)&Xw[(size_t)row * 512 + c] = v;
    } else {
        v = *(const float2*)&X[(size_t)row * 512 + c];
        if (X2 && (row & 1023) >= 512) {
            float2 v2 = *(const float2*)&X2[(size_t)row * 512 + c];
            v.x += v2.x; v.y += v2.y;
        }
    }

    float s = v.x + v.y;
    #pragma unroll
    for (int off = 1; off < 64; off <<= 1) s += __shfl_xor(s, off);
    if ((threadIdx.x & 63) == 0) sbuf[threadIdx.x >> 6] = s;
    __syncthreads();
    s = sbuf[0] + sbuf[1] + sbuf[2] + sbuf[3];
    float mu = s * (1.0f / 512.0f);
    float dx = v.x - mu, dy = v.y - mu;
    float ss = dx * dx + dy * dy;
    __syncthreads();
    #pragma unroll
    for (int off = 1; off < 64; off <<= 1) ss += __shfl_xor(ss, off);
    if ((threadIdx.x & 63) == 0) sbuf[threadIdx.x >> 6] = ss;
    __syncthreads();
    ss = sbuf[0] + sbuf[1] + sbuf[2] + sbuf[3];
    float rs = rsqrtf(ss * (1.0f / 512.0f) + 1e-6f);

    float o0 = dx * rs * g[c] + bt[c];
    float o1 = dy * rs * g[c + 1] + bt[c + 1];
    if (U) {
        o0 *= (float)U[(size_t)row * 2048 + c];
        o1 *= (float)U[(size_t)row * 2048 + c + 1];
    }
    h2 o;
    o[0] = (_Float16)o0; o[1] = (_Float16)o1;
    *(h2*)&O[(size_t)row * 512 + c] = o;
}

// ---------------------------------------------------------------- MFMA GEMM (fp16 in, f32 acc)
template<int EPI, int BM, int BN>
__global__ __launch_bounds__(256) void k_gemm(const _Float16* __restrict__ A,
                                              const _Float16* __restrict__ Bm,
                                              int K, int Ncols,
                                              _Float16* __restrict__ Cu,
                                              _Float16* __restrict__ vT,
                                              const float* __restrict__ bo,
                                              const int* __restrict__ slen,
                                              float* __restrict__ Xio) {
    constexpr int WR = BM / 32;
    constexpr int WC = BN / 32;
    __shared__ _Float16 As[2][BM * 64];
    __shared__ _Float16 Bs[2][BN * 64];
    int tid = threadIdx.x;
    int w = tid >> 6, lane = tid & 63;
    int t = lane & 15, gq = lane >> 4;
    int row0 = blockIdx.y * BM, col0 = blockIdx.x * BN;
    int wr = (w >> 1) * (BM / 2), wc = (w & 1) * (BN / 2);

    f4 zero4 = {0.0f, 0.0f, 0.0f, 0.0f};
    f4 acc[WR][WC];
    #pragma unroll
    for (int i = 0; i < WR; ++i)
        #pragma unroll
        for (int j = 0; j < WC; ++j) acc[i][j] = zero4;

    auto stage = [&](int buf, int k0) {
        #pragma unroll
        for (int q = 0; q < BM / 32; ++q) {
            int s = ((q << 2) + w) * 64 + lane;
            int r = s >> 3, cs = (s & 7) ^ (r & 7);
            gl16(A + (size_t)(row0 + r) * K + k0 + (cs << 3),
                 (char*)&As[buf][0] + (size_t)((q << 2) + w) * 1024);
        }
        #pragma unroll
        for (int q = 0; q < BN / 32; ++q) {
            int s = ((q << 2) + w) * 64 + lane;
            int r = s >> 3, cs = (s & 7) ^ (r & 7);
            gl16(Bm + (size_t)(col0 + r) * K + k0 + (cs << 3),
                 (char*)&Bs[buf][0] + (size_t)((q << 2) + w) * 1024);
        }
    };

    stage(0, 0);
    int cur = 0;
    for (int k0 = 0; k0 < K; k0 += 64) {
        __syncthreads();
        if (k0 + 64 < K) stage(cur ^ 1, k0 + 64);
        h8 af[WR][2], bf[WC][2];
        #pragma unroll
        for (int i = 0; i < WR; ++i) {
            int rl = wr + (i << 4) + t;
            #pragma unroll
            for (int ks = 0; ks < 2; ++ks)
                af[i][ks] = *(const h8*)((const char*)&As[cur][0] + rl * 128 +
                                         (((gq + (ks << 2)) ^ (rl & 7)) << 4));
        }
        #pragma unroll
        for (int j = 0; j < WC; ++j) {
            int nl = wc + (j << 4) + t;
            #pragma unroll
            for (int ks = 0; ks < 2; ++ks)
                bf[j][ks] = *(const h8*)((const char*)&Bs[cur][0] + nl * 128 +
                                         (((gq + (ks << 2)) ^ (nl & 7)) << 4));
        }
        #pragma unroll
        for (int i = 0; i < WR; ++i)
            #pragma unroll
            for (int j = 0; j < WC; ++j) {
                acc[i][j] = __builtin_amdgcn_mfma_f32_16x16x32_f16(af[i][0], bf[j][0], acc[i][j], 0, 0, 0);
                acc[i][j] = __builtin_amdgcn_mfma_f32_16x16x32_f16(af[i][1], bf[j][1], acc[i][j], 0, 0, 0);
            }
        cur ^= 1;
    }

    #pragma unroll
    for (int i = 0; i < WR; ++i) {
        #pragma unroll
        for (int j = 0; j < WC; ++j) {
            int colf = col0 + wc + (j << 4) + t;
            int rowb = row0 + wr + (i << 4) + (gq << 2);
            if (EPI == 0) {
                if (colf >= 512 && colf < 1024) {
                    int b = rowb >> 10;
                    int hh = (colf - 512) >> 6, dd = (colf - 512) & 63;
                    h4 pk;
                    #pragma unroll
                    for (int rr = 0; rr < 4; ++rr) pk[rr] = (_Float16)fast_silu(acc[i][j][rr]);
                    size_t off = ((size_t)((b << 3) + hh) * 64 + dd) * 1024 + (rowb & 1023);
                    *(h4*)&vT[off] = pk;
                } else {
                    #pragma unroll
                    for (int rr = 0; rr < 4; ++rr)
                        Cu[(size_t)(rowb + rr) * 2048 + colf] = (_Float16)fast_silu(acc[i][j][rr]);
                }
            } else {
                int b = rowb >> 10;
                #pragma unroll
                for (int rr = 0; rr < 4; ++rr) {
                    int row = rowb + rr;
                    float m = ((row & 1023) < slen[b]) ? 1.0f : 0.0f;
                    size_t ix = (size_t)row * 512 + colf;
                    Xio[ix] = (Xio[ix] + acc[i][j][rr] + bo[colf]) * m;
                }
            }
        }
    }
}

// ---------------------------------------------------------------- fused attention (MFMA, swapped QK^T)
__global__ __launch_bounds__(256) void k_attn(const _Float16* __restrict__ uvqk,
                                              const _Float16* __restrict__ vT,
                                              const float* __restrict__ posw,
                                              float* __restrict__ av0,
                                              float* __restrict__ av1) {
    __shared__ _Float16 Ks[2][64 * 64];   // 16 KB (Ks[1] doubles as Q staging)
    __shared__ _Float16 Vs[64 * 64];      // 8 KB, single-buffered
    __shared__ _Float16 Ps[64 * 72];      // 9.2 KB, row stride 144 B
    __shared__ float pws[2][128];         // 1 KB
    int tid = threadIdx.x;
    int w = tid >> 6, lane = tid & 63;
    int t = lane & 15, gq = lane >> 4;
    int b = blockIdx.z, h = blockIdx.y, x = blockIdx.x;

    int nt, mlo, mhi;
    float* avout;
    if (x < 8) { nt = x; mlo = 0; mhi = nt; avout = av0; }
    else {
        int p = x - 8;
        nt = 8 + (p >> 1);
        int c0 = (nt + 2) >> 1;
        if (p & 1) { mlo = c0; mhi = nt; avout = av1; }
        else       { mlo = 0;  mhi = c0 - 1; avout = av0; }
    }
    int n0 = nt << 6;

    const _Float16* qbase = uvqk + (size_t)b * NN * 2048 + 1024 + h * 64;
    const _Float16* kbase = uvqk + (size_t)b * NN * 2048 + 1536 + h * 64;
    const _Float16* vbase = vT + (size_t)((b << 3) + h) * 64 * 1024;

    // prologue: Q -> Ks[1], K(mlo) -> Ks[0], pws[0]
    #pragma unroll
    for (int q = 0; q < 2; ++q) {
        int s = (((w << 1) + q) << 6) + lane;
        int r = s >> 3, cs = (s & 7) ^ (r & 7);
        gl16(qbase + (size_t)(n0 + r) * 2048 + (cs << 3),
             (char*)&Ks[1][0] + (size_t)(((w << 1) + q) << 6) * 16);
        gl16(kbase + (size_t)((mlo << 6) + r) * 2048 + (cs << 3),
             (char*)&Ks[0][0] + (size_t)(((w << 1) + q) << 6) * 16);
    }
    if (tid < 128) pws[0][tid] = posw[(mlo << 6) - n0 + tid + 960];
    __syncthreads();

    h8 aq[2];
    {
        int rl = (w << 4) + t;
        #pragma unroll
        for (int ks = 0; ks < 2; ++ks)
            aq[ks] = *(const h8*)((const char*)&Ks[1][0] + rl * 128 +
                                  (((gq + (ks << 2)) ^ (rl & 7)) << 4));
    }
    asm volatile("s_waitcnt lgkmcnt(0)" ::: "memory");
    __builtin_amdgcn_sched_barrier(0);
    __syncthreads();   // all waves hold aq before Ks[1] is overwritten by prefetch

    f4 zero4 = {0.0f, 0.0f, 0.0f, 0.0f};
    f4 avacc[4];
    #pragma unroll
    for (int j = 0; j < 4; ++j) avacc[j] = zero4;

    int cur = 0;
    for (int mt = mlo; mt <= mhi; ++mt) {
        int m0 = mt << 6;
        // stage V(mt) first (oldest vmem), then K(next) prefetch, then pws prefetch
        #pragma unroll
        for (int q = 0; q < 2; ++q) {
            int s = (((w << 1) + q) << 6) + lane;
            int r = s >> 3, cs = (s & 7) ^ (r & 7);
            gl16(vbase + (size_t)r * 1024 + m0 + (cs << 3),
                 (char*)&Vs[0] + (size_t)(((w << 1) + q) << 6) * 16);
        }
        int mt2 = (mt < mhi) ? mt + 1 : mt;   // clamped: keeps vmcnt count uniform
        #pragma unroll
        for (int q = 0; q < 2; ++q) {
            int s = (((w << 1) + q) << 6) + lane;
            int r = s >> 3, cs = (s & 7) ^ (r & 7);
            gl16(kbase + (size_t)((mt2 << 6) + r) * 2048 + (cs << 3),
                 (char*)&Ks[cur ^ 1][0] + (size_t)(((w << 1) + q) << 6) * 16);
        }
        if (tid < 128) pws[cur ^ 1][tid] = posw[(mt2 << 6) - n0 + tid + 960];

        // S^T = K Q^T with rel-pos bias folded into MFMA C-in
        f4 sacc[4];
        #pragma unroll
        for (int i = 0; i < 4; ++i) {
            f4 binit;
            #pragma unroll
            for (int rr = 0; rr < 4; ++rr)
                binit[rr] = pws[cur][63 + (i << 4) + (gq << 2) + rr - ((w << 4) + t)];
            int ml = (i << 4) + t;
            h8 ak0 = *(const h8*)((const char*)&Ks[cur][0] + ml * 128 + (((gq + 0) ^ (ml & 7)) << 4));
            h8 ak1 = *(const h8*)((const char*)&Ks[cur][0] + ml * 128 + (((gq + 4) ^ (ml & 7)) << 4));
            sacc[i] = __builtin_amdgcn_mfma_f32_16x16x32_f16(ak0, aq[0], binit, 0, 0, 0);
            sacc[i] = __builtin_amdgcn_mfma_f32_16x16x32_f16(ak1, aq[1], sacc[i], 0, 0, 0);
        }
        // P = silu(S)*causal, packed h4 (4 consecutive m per lane) -> b64 LDS writes
        int nabs = n0 + (w << 4) + t;
        #pragma unroll
        for (int i = 0; i < 4; ++i) {
            int mb = m0 + (i << 4) + (gq << 2);
            h4 pk;
            #pragma unroll
            for (int rr = 0; rr < 4; ++rr) {
                float p = (mb + rr <= nabs) ? fast_silu(sacc[i][rr]) : 0.0f;
                pk[rr] = (_Float16)p;
            }
            *(h4*)((char*)Ps + ((w << 4) + t) * 144 + (i << 5) + (gq << 3)) = pk;
        }
        asm volatile("s_waitcnt lgkmcnt(0)" ::: "memory");  // own-wave Ps rows visible
        asm volatile("s_waitcnt vmcnt(2)" ::: "memory");    // V landed; K(next) stays in flight
        __builtin_amdgcn_s_barrier();                       // all waves' V landed
        // AV += P @ V
        #pragma unroll
        for (int ks = 0; ks < 2; ++ks) {
            h8 pa = *(const h8*)((const char*)Ps + ((w << 4) + t) * 144 + (ks << 6) + (gq << 4));
            #pragma unroll
            for (int jt = 0; jt < 4; ++jt) {
                int dl = (jt << 4) + t;
                h8 bv = *(const h8*)((const char*)&Vs[0] + dl * 128 +
                                     (((gq + (ks << 2)) ^ (dl & 7)) << 4));
                avacc[jt] = __builtin_amdgcn_mfma_f32_16x16x32_f16(pa, bv, avacc[jt], 0, 0, 0);
            }
        }
        __syncthreads();   // PV reads done before next-iter Vs/Ks overwrite; drains vmcnt
        cur ^= 1;
    }

    #pragma unroll
    for (int jt = 0; jt < 4; ++jt) {
        #pragma unroll
        for (int rr = 0; rr < 4; ++rr) {
            int n = n0 + (w << 4) + (gq << 2) + rr;
            int d = (jt << 4) + t;
            avout[(size_t)(b * NN + n) * 512 + h * 64 + d] = avacc[jt][rr] * (1.0f / 1024.0f);
        }
    }
}

// ---------------------------------------------------------------- final L2 norm
__global__ __launch_bounds__(256) void k_norm(float* __restrict__ X) {
    __shared__ float sbuf[4];
    int row = blockIdx.x;
    int c = threadIdx.x << 1;
    float2 v = *(const float2*)&X[(size_t)row * 512 + c];
    float ss = v.x * v.x + v.y * v.y;
    #pragma unroll
    for (int off = 1; off < 64; off <<= 1) ss += __shfl_xor(ss, off);
    if ((threadIdx.x & 63) == 0) sbuf[threadIdx.x >> 6] = ss;
    __syncthreads();
    ss = sbuf[0] + sbuf[1] + sbuf[2] + sbuf[3];
    float norm = sqrtf(ss);
    float sc = 1.0f / fmaxf(norm, 1e-6f);
    X[(size_t)row * 512 + c] = v.x * sc;
    X[(size_t)row * 512 + c + 1] = v.y * sc;
}

// ---------------------------------------------------------------- launch
extern "C" void kernel_launch(void* const* d_in, const int* in_sizes, int n_in,
                              void* d_out, int out_size, void* d_ws, size_t ws_size,
                              hipStream_t stream) {
    const float* seq   = (const float*)d_in[0];
    const int*   slen  = (const int*)d_in[1];
    const float* pos   = (const float*)d_in[2];
    const float* ln1g  = (const float*)d_in[3];
    const float* ln1b  = (const float*)d_in[4];
    const float* wuvqk = (const float*)d_in[5];
    const float* ln2g  = (const float*)d_in[6];
    const float* ln2b  = (const float*)d_in[7];
    const float* wo    = (const float*)d_in[8];
    const float* bo    = (const float*)d_in[9];
    const float* posw  = (const float*)d_in[10];

    float* x = (float*)d_out;
    char* W = (char*)d_ws;
    _Float16* nx16   = (_Float16*)(W);                       // 4 MiB
    _Float16* oin16  = (_Float16*)(W + (4u << 20));          // 4 MiB
    _Float16* uvqk16 = (_Float16*)(W + (8u << 20));          // 16 MiB
    _Float16* vT16   = (_Float16*)(W + (24u << 20));         // 4 MiB [b][h][d][n]
    float*    av0    = (float*)   (W + (28u << 20));         // 8 MiB
    float*    av1    = (float*)   (W + (36u << 20));         // 8 MiB
    _Float16* wuT16  = (_Float16*)(W + (44u << 20));         // 8 MiB [l][2048][512]
    _Float16* woT16  = (_Float16*)(W + (52u << 20));         // 2 MiB [l][512][512]

    k_transpose16<<<dim3(32, 8, NBL), 256, 0, stream>>>(wuvqk, wuT16, 512, 2048);
    k_transpose16<<<dim3(8, 8, NBL), 256, 0, stream>>>(wo, woT16, 512, 512);
    for (int l = 0; l < NBL; ++l) {
        if (l == 0)
            k_ln<1><<<ROWS, 256, 0, stream>>>(nullptr, nullptr, seq, pos, slen,
                                              ln1g, ln1b, nx16, nullptr, x);
        else
            k_ln<0><<<ROWS, 256, 0, stream>>>(x, nullptr, nullptr, nullptr, nullptr,
                                              ln1g + l * 512, ln1b + l * 512, nx16, nullptr, nullptr);
        k_gemm<0, 128, 128><<<dim3(16, 32), 256, 0, stream>>>(
            nx16, wuT16 + (size_t)l * 2048 * 512, 512, 2048, uvqk16, vT16, nullptr, nullptr, nullptr);
        k_attn<<<dim3(24, 8, NBL), 256, 0, stream>>>(uvqk16, vT16, posw + l * (2 * NN - 1), av0, av1);
        k_ln<0><<<ROWS, 256, 0, stream>>>(av0, av1, nullptr, nullptr, nullptr,
                                          ln2g + l * 512, ln2b + l * 512, oin16, uvqk16, nullptr);
        k_gemm<1, 64, 64><<<dim3(8, 64), 256, 0, stream>>>(
            oin16, woT16 + (size_t)l * 512 * 512, 512, 512, nullptr, nullptr, bo + l * 512, slen, x);
    }
    k_norm<<<ROWS, 256, 0, stream>>>(x);
}

// Round 5
// 238.960 us; speedup vs baseline: 5.3036x; 1.0637x over previous
//
#include <hip/hip_runtime.h>
#include <math.h>
#include <stdint.h>

#define BB 4
#define NN 1024
#define DD 512
#define HH 8
#define ROWS (BB * NN)   // 4096
#define NBL 4

typedef _Float16 h8 __attribute__((ext_vector_type(8)));
typedef _Float16 h4 __attribute__((ext_vector_type(4)));
typedef _Float16 h2 __attribute__((ext_vector_type(2)));
typedef float f4 __attribute__((ext_vector_type(4)));

__device__ __forceinline__ float fast_silu(float x) {
    float e = __builtin_amdgcn_exp2f(-1.4426950408889634f * x);
    return x * __builtin_amdgcn_rcpf(1.0f + e);
}

// async global->LDS, 16B/lane; LDS dest = wave-uniform base + lane*16
__device__ __forceinline__ void gl16(const void* gp, void* lp) {
    __builtin_amdgcn_global_load_lds(
        (const __attribute__((address_space(1))) uint32_t*)gp,
        (__attribute__((address_space(3))) uint32_t*)lp, 16, 0, 0);
}

// ---------------------------------------------------------------- transpose+fp16 convert (both weights)
// z<4: wuvqk layer z (512x2048); z>=4: wo layer z-4 (512x512, only x<8 active)
__global__ __launch_bounds__(256) void k_transpose16(const float* __restrict__ wuvqk,
                                                     _Float16* __restrict__ wuT,
                                                     const float* __restrict__ wo,
                                                     _Float16* __restrict__ woT) {
    __shared__ _Float16 T[64][66];
    int z = blockIdx.z;
    const float* s; _Float16* d; int N;
    if (z < 4) { N = 2048; s = wuvqk + (size_t)z * 512 * 2048; d = wuT + (size_t)z * 2048 * 512; }
    else {
        if (blockIdx.x >= 8) return;
        N = 512; s = wo + (size_t)(z - 4) * 512 * 512; d = woT + (size_t)(z - 4) * 512 * 512;
    }
    int n0 = blockIdx.x << 6, k0 = blockIdx.y << 6;
    int tx = threadIdx.x & 63, ty = threadIdx.x >> 6;
    #pragma unroll
    for (int q = 0; q < 16; ++q)
        T[(q << 2) + ty][tx] = (_Float16)s[(size_t)(k0 + (q << 2) + ty) * N + n0 + tx];
    __syncthreads();
    #pragma unroll
    for (int q = 0; q < 16; ++q)
        d[(size_t)(n0 + (q << 2) + ty) * 512 + k0 + tx] = T[tx][(q << 2) + ty];
}

// ---------------------------------------------------------------- layernorm -> fp16
// INIT=1: v = (seq*sqrt(D)+pos)*mask computed on the fly, written to Xw, then LN'd.
// X2 added for (row&1023)>=384, X3 for >=768 (attn 2/3-way split partials). U: *u.
template<int INIT>
__global__ __launch_bounds__(256) void k_ln(const float* __restrict__ X,
                                            const float* __restrict__ X2,
                                            const float* __restrict__ X3,
                                            const float* __restrict__ seq,
                                            const float* __restrict__ pos,
                                            const int* __restrict__ slen,
                                            const float* __restrict__ g,
                                            const float* __restrict__ bt,
                                            _Float16* __restrict__ O,
                                            const _Float16* __restrict__ U,
                                            float* __restrict__ Xw) {
    __shared__ float sbuf[4];
    int row = blockIdx.x;
    int c = threadIdx.x << 1;
    float2 v;
    if (INIT) {
        int b = row >> 10, n = row & (NN - 1);
        float m = (n < slen[b]) ? 1.0f : 0.0f;
        float2 s2 = *(const float2*)&seq[(size_t)row * 512 + c];
        float2 p2 = *(const float2*)&pos[(size_t)n * 512 + c];
        const float SD = 22.627416997969522f;
        v.x = (s2.x * SD + p2.x) * m;
        v.y = (s2.y * SD + p2.y) * m;
        *(float2*)&Xw[(size_t)row * 512 + c] = v;
    } else {
        v = *(const float2*)&X[(size_t)row * 512 + c];
        int nn = row & 1023;
        if (X2 && nn >= 384) {
            float2 v2 = *(const float2*)&X2[(size_t)row * 512 + c];
            v.x += v2.x; v.y += v2.y;
        }
        if (X3 && nn >= 768) {
            float2 v3 = *(const float2*)&X3[(size_t)row * 512 + c];
            v.x += v3.x; v.y += v3.y;
        }
    }

    float s = v.x + v.y;
    #pragma unroll
    for (int off = 1; off < 64; off <<= 1) s += __shfl_xor(s, off);
    if ((threadIdx.x & 63) == 0) sbuf[threadIdx.x >> 6] = s;
    __syncthreads();
    s = sbuf[0] + sbuf[1] + sbuf[2] + sbuf[3];
    float mu = s * (1.0f / 512.0f);
    float dx = v.x - mu, dy = v.y - mu;
    float ss = dx * dx + dy * dy;
    __syncthreads();
    #pragma unroll
    for (int off = 1; off < 64; off <<= 1) ss += __shfl_xor(ss, off);
    if ((threadIdx.x & 63) == 0) sbuf[threadIdx.x >> 6] = ss;
    __syncthreads();
    ss = sbuf[0] + sbuf[1] + sbuf[2] + sbuf[3];
    float rs = rsqrtf(ss * (1.0f / 512.0f) + 1e-6f);

    float o0 = dx * rs * g[c] + bt[c];
    float o1 = dy * rs * g[c + 1] + bt[c + 1];
    if (U) {
        o0 *= (float)U[(size_t)row * 2048 + c];
        o1 *= (float)U[(size_t)row * 2048 + c + 1];
    }
    h2 o;
    o[0] = (_Float16)o0; o[1] = (_Float16)o1;
    *(h2*)&O[(size_t)row * 512 + c] = o;
}

// ---------------------------------------------------------------- MFMA GEMM (fp16 in, f32 acc)
template<int EPI, int BM, int BN>
__global__ __launch_bounds__(256) void k_gemm(const _Float16* __restrict__ A,
                                              const _Float16* __restrict__ Bm,
                                              int K, int Ncols,
                                              _Float16* __restrict__ Cu,
                                              _Float16* __restrict__ vT,
                                              const float* __restrict__ bo,
                                              const int* __restrict__ slen,
                                              float* __restrict__ Xio) {
    constexpr int WR = BM / 32;
    constexpr int WC = BN / 32;
    __shared__ _Float16 As[2][BM * 64];
    __shared__ _Float16 Bs[2][BN * 64];
    int tid = threadIdx.x;
    int w = tid >> 6, lane = tid & 63;
    int t = lane & 15, gq = lane >> 4;
    // XCD-aware chunked swizzle (grid size % 8 == 0): row-panel groups per XCD
    int flat = blockIdx.y * gridDim.x + blockIdx.x;
    int cpx = (gridDim.x * gridDim.y) >> 3;
    int f2 = (flat & 7) * cpx + (flat >> 3);
    int bx = f2 % gridDim.x, by = f2 / gridDim.x;
    int row0 = by * BM, col0 = bx * BN;
    int wr = (w >> 1) * (BM / 2), wc = (w & 1) * (BN / 2);

    f4 zero4 = {0.0f, 0.0f, 0.0f, 0.0f};
    f4 acc[WR][WC];
    #pragma unroll
    for (int i = 0; i < WR; ++i)
        #pragma unroll
        for (int j = 0; j < WC; ++j) acc[i][j] = zero4;

    auto stage = [&](int buf, int k0) {
        #pragma unroll
        for (int q = 0; q < BM / 32; ++q) {
            int s = ((q << 2) + w) * 64 + lane;
            int r = s >> 3, cs = (s & 7) ^ (r & 7);
            gl16(A + (size_t)(row0 + r) * K + k0 + (cs << 3),
                 (char*)&As[buf][0] + (size_t)((q << 2) + w) * 1024);
        }
        #pragma unroll
        for (int q = 0; q < BN / 32; ++q) {
            int s = ((q << 2) + w) * 64 + lane;
            int r = s >> 3, cs = (s & 7) ^ (r & 7);
            gl16(Bm + (size_t)(col0 + r) * K + k0 + (cs << 3),
                 (char*)&Bs[buf][0] + (size_t)((q << 2) + w) * 1024);
        }
    };

    stage(0, 0);
    int cur = 0;
    for (int k0 = 0; k0 < K; k0 += 64) {
        __syncthreads();
        if (k0 + 64 < K) stage(cur ^ 1, k0 + 64);
        h8 af[WR][2], bf[WC][2];
        #pragma unroll
        for (int i = 0; i < WR; ++i) {
            int rl = wr + (i << 4) + t;
            #pragma unroll
            for (int ks = 0; ks < 2; ++ks)
                af[i][ks] = *(const h8*)((const char*)&As[cur][0] + rl * 128 +
                                         (((gq + (ks << 2)) ^ (rl & 7)) << 4));
        }
        #pragma unroll
        for (int j = 0; j < WC; ++j) {
            int nl = wc + (j << 4) + t;
            #pragma unroll
            for (int ks = 0; ks < 2; ++ks)
                bf[j][ks] = *(const h8*)((const char*)&Bs[cur][0] + nl * 128 +
                                         (((gq + (ks << 2)) ^ (nl & 7)) << 4));
        }
        #pragma unroll
        for (int i = 0; i < WR; ++i)
            #pragma unroll
            for (int j = 0; j < WC; ++j) {
                acc[i][j] = __builtin_amdgcn_mfma_f32_16x16x32_f16(af[i][0], bf[j][0], acc[i][j], 0, 0, 0);
                acc[i][j] = __builtin_amdgcn_mfma_f32_16x16x32_f16(af[i][1], bf[j][1], acc[i][j], 0, 0, 0);
            }
        cur ^= 1;
    }

    #pragma unroll
    for (int i = 0; i < WR; ++i) {
        #pragma unroll
        for (int j = 0; j < WC; ++j) {
            int colf = col0 + wc + (j << 4) + t;
            int rowb = row0 + wr + (i << 4) + (gq << 2);
            if (EPI == 0) {
                if (colf >= 512 && colf < 1024) {
                    int b = rowb >> 10;
                    int hh = (colf - 512) >> 6, dd = (colf - 512) & 63;
                    h4 pk;
                    #pragma unroll
                    for (int rr = 0; rr < 4; ++rr) pk[rr] = (_Float16)fast_silu(acc[i][j][rr]);
                    size_t off = ((size_t)((b << 3) + hh) * 64 + dd) * 1024 + (rowb & 1023);
                    *(h4*)&vT[off] = pk;
                } else {
                    #pragma unroll
                    for (int rr = 0; rr < 4; ++rr)
                        Cu[(size_t)(rowb + rr) * 2048 + colf] = (_Float16)fast_silu(acc[i][j][rr]);
                }
            } else {
                int b = rowb >> 10;
                #pragma unroll
                for (int rr = 0; rr < 4; ++rr) {
                    int row = rowb + rr;
                    float m = ((row & 1023) < slen[b]) ? 1.0f : 0.0f;
                    size_t ix = (size_t)row * 512 + colf;
                    Xio[ix] = (Xio[ix] + acc[i][j][rr] + bo[colf]) * m;
                }
            }
        }
    }
}

// ---------------------------------------------------------------- fused attention (MFMA, swapped QK^T)
// 30 work-units per (b,h): nt<6 whole -> av0; nt 6..11 2-way -> av0/av1;
// nt 12..15 3-way -> av0/av1/av2. Summed in k_ln (thresholds 384/768).
__global__ __launch_bounds__(256) void k_attn(const _Float16* __restrict__ uvqk,
                                              const _Float16* __restrict__ vT,
                                              const float* __restrict__ posw,
                                              float* __restrict__ av0,
                                              float* __restrict__ av1,
                                              float* __restrict__ av2) {
    __shared__ _Float16 Ks[2][64 * 64];   // 16 KB (Ks[1] doubles as Q staging)
    __shared__ _Float16 Vs[64 * 64];      // 8 KB, single-buffered
    __shared__ _Float16 Ps[64 * 72];      // 9.2 KB, row stride 144 B
    __shared__ float pws[2][128];         // 1 KB
    int tid = threadIdx.x;
    int w = tid >> 6, lane = tid & 63;
    int t = lane & 15, gq = lane >> 4;
    // XCD-aware swizzle over 960 blocks: 120 consecutive units (4 (b,h) groups) per XCD
    int flat = blockIdx.x + 30 * (blockIdx.y + 8 * blockIdx.z);
    int f2 = (flat & 7) * 120 + (flat >> 3);
    int u = f2 % 30, h = (f2 / 30) & 7, b = f2 / 240;

    int nt, mlo, mhi;
    float* avout;
    if (u < 6) { nt = u; mlo = 0; mhi = nt; avout = av0; }
    else if (u < 18) {
        int p = u - 6; nt = 6 + (p >> 1);
        int c0 = (nt + 2) >> 1;
        if (p & 1) { mlo = c0; mhi = nt; avout = av1; }
        else       { mlo = 0;  mhi = c0 - 1; avout = av0; }
    } else {
        int p = u - 18; int third = p / 3; nt = 12 + third; int q3 = p - 3 * third;
        int c = nt + 1;
        int c1 = (c + 2) / 3, c2 = (2 * c + 2) / 3;
        if (q3 == 0)      { mlo = 0;  mhi = c1 - 1; avout = av0; }
        else if (q3 == 1) { mlo = c1; mhi = c2 - 1; avout = av1; }
        else              { mlo = c2; mhi = nt;     avout = av2; }
    }
    int n0 = nt << 6;

    const _Float16* qbase = uvqk + (size_t)b * NN * 2048 + 1024 + h * 64;
    const _Float16* kbase = uvqk + (size_t)b * NN * 2048 + 1536 + h * 64;
    const _Float16* vbase = vT + (size_t)((b << 3) + h) * 64 * 1024;

    // prologue: Q -> Ks[1], K(mlo) -> Ks[0], pws[0]
    #pragma unroll
    for (int q = 0; q < 2; ++q) {
        int s = (((w << 1) + q) << 6) + lane;
        int r = s >> 3, cs = (s & 7) ^ (r & 7);
        gl16(qbase + (size_t)(n0 + r) * 2048 + (cs << 3),
             (char*)&Ks[1][0] + (size_t)(((w << 1) + q) << 6) * 16);
        gl16(kbase + (size_t)((mlo << 6) + r) * 2048 + (cs << 3),
             (char*)&Ks[0][0] + (size_t)(((w << 1) + q) << 6) * 16);
    }
    if (tid < 128) pws[0][tid] = posw[(mlo << 6) - n0 + tid + 960];
    __syncthreads();

    h8 aq[2];
    {
        int rl = (w << 4) + t;
        #pragma unroll
        for (int ks = 0; ks < 2; ++ks)
            aq[ks] = *(const h8*)((const char*)&Ks[1][0] + rl * 128 +
                                  (((gq + (ks << 2)) ^ (rl & 7)) << 4));
    }
    asm volatile("s_waitcnt lgkmcnt(0)" ::: "memory");
    __builtin_amdgcn_sched_barrier(0);
    __syncthreads();   // all waves hold aq before Ks[1] is overwritten by prefetch

    f4 zero4 = {0.0f, 0.0f, 0.0f, 0.0f};
    f4 avacc[4];
    #pragma unroll
    for (int j = 0; j < 4; ++j) avacc[j] = zero4;

    int cur = 0;
    for (int mt = mlo; mt <= mhi; ++mt) {
        int m0 = mt << 6;
        // stage V(mt) first (oldest vmem), then K(next) prefetch, then pws prefetch
        #pragma unroll
        for (int q = 0; q < 2; ++q) {
            int s = (((w << 1) + q) << 6) + lane;
            int r = s >> 3, cs = (s & 7) ^ (r & 7);
            gl16(vbase + (size_t)r * 1024 + m0 + (cs << 3),
                 (char*)&Vs[0] + (size_t)(((w << 1) + q) << 6) * 16);
        }
        int mt2 = (mt < mhi) ? mt + 1 : mt;   // clamped: keeps vmcnt count uniform
        #pragma unroll
        for (int q = 0; q < 2; ++q) {
            int s = (((w << 1) + q) << 6) + lane;
            int r = s >> 3, cs = (s & 7) ^ (r & 7);
            gl16(kbase + (size_t)((mt2 << 6) + r) * 2048 + (cs << 3),
                 (char*)&Ks[cur ^ 1][0] + (size_t)(((w << 1) + q) << 6) * 16);
        }
        if (tid < 128) pws[cur ^ 1][tid] = posw[(mt2 << 6) - n0 + tid + 960];

        // S^T = K Q^T with rel-pos bias folded into MFMA C-in
        f4 sacc[4];
        __builtin_amdgcn_s_setprio(1);
        #pragma unroll
        for (int i = 0; i < 4; ++i) {
            f4 binit;
            #pragma unroll
            for (int rr = 0; rr < 4; ++rr)
                binit[rr] = pws[cur][63 + (i << 4) + (gq << 2) + rr - ((w << 4) + t)];
            int ml = (i << 4) + t;
            h8 ak0 = *(const h8*)((const char*)&Ks[cur][0] + ml * 128 + (((gq + 0) ^ (ml & 7)) << 4));
            h8 ak1 = *(const h8*)((const char*)&Ks[cur][0] + ml * 128 + (((gq + 4) ^ (ml & 7)) << 4));
            sacc[i] = __builtin_amdgcn_mfma_f32_16x16x32_f16(ak0, aq[0], binit, 0, 0, 0);
            sacc[i] = __builtin_amdgcn_mfma_f32_16x16x32_f16(ak1, aq[1], sacc[i], 0, 0, 0);
        }
        __builtin_amdgcn_s_setprio(0);
        // P = silu(S)*causal, packed h4 (4 consecutive m per lane) -> b64 LDS writes
        int nabs = n0 + (w << 4) + t;
        #pragma unroll
        for (int i = 0; i < 4; ++i) {
            int mb = m0 + (i << 4) + (gq << 2);
            h4 pk;
            #pragma unroll
            for (int rr = 0; rr < 4; ++rr) {
                float p = (mb + rr <= nabs) ? fast_silu(sacc[i][rr]) : 0.0f;
                pk[rr] = (_Float16)p;
            }
            *(h4*)((char*)Ps + ((w << 4) + t) * 144 + (i << 5) + (gq << 3)) = pk;
        }
        asm volatile("s_waitcnt lgkmcnt(0)" ::: "memory");  // own-wave Ps rows visible
        asm volatile("s_waitcnt vmcnt(2)" ::: "memory");    // V landed; K(next) stays in flight
        __builtin_amdgcn_s_barrier();                       // all waves' V landed
        // AV += P @ V
        __builtin_amdgcn_s_setprio(1);
        #pragma unroll
        for (int ks = 0; ks < 2; ++ks) {
            h8 pa = *(const h8*)((const char*)Ps + ((w << 4) + t) * 144 + (ks << 6) + (gq << 4));
            #pragma unroll
            for (int jt = 0; jt < 4; ++jt) {
                int dl = (jt << 4) + t;
                h8 bv = *(const h8*)((const char*)&Vs[0] + dl * 128 +
                                     (((gq + (ks << 2)) ^ (dl & 7)) << 4));
                avacc[jt] = __builtin_amdgcn_mfma_f32_16x16x32_f16(pa, bv, avacc[jt], 0, 0, 0);
            }
        }
        __builtin_amdgcn_s_setprio(0);
        __syncthreads();   // PV reads done before next-iter Vs/Ks overwrite; drains vmcnt
        cur ^= 1;
    }

    #pragma unroll
    for (int jt = 0; jt < 4; ++jt) {
        #pragma unroll
        for (int rr = 0; rr < 4; ++rr) {
            int n = n0 + (w << 4) + (gq << 2) + rr;
            int d = (jt << 4) + t;
            avout[(size_t)(b * NN + n) * 512 + h * 64 + d] = avacc[jt][rr] * (1.0f / 1024.0f);
        }
    }
}

// ---------------------------------------------------------------- final L2 norm
__global__ __launch_bounds__(256) void k_norm(float* __restrict__ X) {
    __shared__ float sbuf[4];
    int row = blockIdx.x;
    int c = threadIdx.x << 1;
    float2 v = *(const float2*)&X[(size_t)row * 512 + c];
    float ss = v.x * v.x + v.y * v.y;
    #pragma unroll
    for (int off = 1; off < 64; off <<= 1) ss += __shfl_xor(ss, off);
    if ((threadIdx.x & 63) == 0) sbuf[threadIdx.x >> 6] = ss;
    __syncthreads();
    ss = sbuf[0] + sbuf[1] + sbuf[2] + sbuf[3];
    float norm = sqrtf(ss);
    float sc = 1.0f / fmaxf(norm, 1e-6f);
    X[(size_t)row * 512 + c] = v.x * sc;
    X[(size_t)row * 512 + c + 1] = v.y * sc;
}

// ---------------------------------------------------------------- launch
extern "C" void kernel_launch(void* const* d_in, const int* in_sizes, int n_in,
                              void* d_out, int out_size, void* d_ws, size_t ws_size,
                              hipStream_t stream) {
    const float* seq   = (const float*)d_in[0];
    const int*   slen  = (const int*)d_in[1];
    const float* pos   = (const float*)d_in[2];
    const float* ln1g  = (const float*)d_in[3];
    const float* ln1b  = (const float*)d_in[4];
    const float* wuvqk = (const float*)d_in[5];
    const float* ln2g  = (const float*)d_in[6];
    const float* ln2b  = (const float*)d_in[7];
    const float* wo    = (const float*)d_in[8];
    const float* bo    = (const float*)d_in[9];
    const float* posw  = (const float*)d_in[10];

    float* x = (float*)d_out;
    char* W = (char*)d_ws;
    _Float16* nx16   = (_Float16*)(W);                       // 4 MiB
    _Float16* oin16  = (_Float16*)(W + (4u << 20));          // 4 MiB
    _Float16* uvqk16 = (_Float16*)(W + (8u << 20));          // 16 MiB
    _Float16* vT16   = (_Float16*)(W + (24u << 20));         // 4 MiB [b][h][d][n]
    float*    av0    = (float*)   (W + (28u << 20));         // 8 MiB
    float*    av1    = (float*)   (W + (36u << 20));         // 8 MiB
    float*    av2    = (float*)   (W + (44u << 20));         // 8 MiB
    _Float16* wuT16  = (_Float16*)(W + (52u << 20));         // 8 MiB [l][2048][512]
    _Float16* woT16  = (_Float16*)(W + (60u << 20));         // 2 MiB [l][512][512]

    k_transpose16<<<dim3(32, 8, 8), 256, 0, stream>>>(wuvqk, wuT16, wo, woT16);
    for (int l = 0; l < NBL; ++l) {
        if (l == 0)
            k_ln<1><<<ROWS, 256, 0, stream>>>(nullptr, nullptr, nullptr, seq, pos, slen,
                                              ln1g, ln1b, nx16, nullptr, x);
        else
            k_ln<0><<<ROWS, 256, 0, stream>>>(x, nullptr, nullptr, nullptr, nullptr, nullptr,
                                              ln1g + l * 512, ln1b + l * 512, nx16, nullptr, nullptr);
        k_gemm<0, 128, 128><<<dim3(16, 32), 256, 0, stream>>>(
            nx16, wuT16 + (size_t)l * 2048 * 512, 512, 2048, uvqk16, vT16, nullptr, nullptr, nullptr);
        k_attn<<<dim3(30, 8, NBL), 256, 0, stream>>>(uvqk16, vT16, posw + l * (2 * NN - 1),
                                                     av0, av1, av2);
        k_ln<0><<<ROWS, 256, 0, stream>>>(av0, av1, av2, nullptr, nullptr, nullptr,
                                          ln2g + l * 512, ln2b + l * 512, oin16, uvqk16, nullptr);
        k_gemm<1, 64, 64><<<dim3(8, 64), 256, 0, stream>>>(
            oin16, woT16 + (size_t)l * 512 * 512, 512, 512, nullptr, nullptr, bo + l * 512, slen, x);
    }
    k_norm<<<ROWS, 256, 0, stream>>>(x);
}

// Round 6
// 234.676 us; speedup vs baseline: 5.4005x; 1.0183x over previous
//
#include <hip/hip_runtime.h>
#include <math.h>
#include <stdint.h>

#define BB 4
#define NN 1024
#define DD 512
#define HH 8
#define ROWS (BB * NN)   // 4096
#define NBL 4

typedef _Float16 h8 __attribute__((ext_vector_type(8)));
typedef _Float16 h4 __attribute__((ext_vector_type(4)));
typedef _Float16 h2 __attribute__((ext_vector_type(2)));
typedef float f4 __attribute__((ext_vector_type(4)));

__device__ __forceinline__ float fast_silu(float x) {
    float e = __builtin_amdgcn_exp2f(-1.4426950408889634f * x);
    return x * __builtin_amdgcn_rcpf(1.0f + e);
}

// async global->LDS, 16B/lane; LDS dest = wave-uniform base + lane*16
__device__ __forceinline__ void gl16(const void* gp, void* lp) {
    __builtin_amdgcn_global_load_lds(
        (const __attribute__((address_space(1))) uint32_t*)gp,
        (__attribute__((address_space(3))) uint32_t*)lp, 16, 0, 0);
}

// ---------------------------------------------------------------- transpose+fp16 convert (both weights)
__global__ __launch_bounds__(256) void k_transpose16(const float* __restrict__ wuvqk,
                                                     _Float16* __restrict__ wuT,
                                                     const float* __restrict__ wo,
                                                     _Float16* __restrict__ woT) {
    __shared__ _Float16 T[64][66];
    int z = blockIdx.z;
    const float* s; _Float16* d; int N;
    if (z < 4) { N = 2048; s = wuvqk + (size_t)z * 512 * 2048; d = wuT + (size_t)z * 2048 * 512; }
    else {
        if (blockIdx.x >= 8) return;
        N = 512; s = wo + (size_t)(z - 4) * 512 * 512; d = woT + (size_t)(z - 4) * 512 * 512;
    }
    int n0 = blockIdx.x << 6, k0 = blockIdx.y << 6;
    int tx = threadIdx.x & 63, ty = threadIdx.x >> 6;
    #pragma unroll
    for (int q = 0; q < 16; ++q)
        T[(q << 2) + ty][tx] = (_Float16)s[(size_t)(k0 + (q << 2) + ty) * N + n0 + tx];
    __syncthreads();
    #pragma unroll
    for (int q = 0; q < 16; ++q)
        d[(size_t)(n0 + (q << 2) + ty) * 512 + k0 + tx] = T[tx][(q << 2) + ty];
}

// ---------------------------------------------------------------- layernorm -> fp16
template<int INIT>
__global__ __launch_bounds__(256) void k_ln(const float* __restrict__ X,
                                            const float* __restrict__ X2,
                                            const float* __restrict__ X3,
                                            const float* __restrict__ seq,
                                            const float* __restrict__ pos,
                                            const int* __restrict__ slen,
                                            const float* __restrict__ g,
                                            const float* __restrict__ bt,
                                            _Float16* __restrict__ O,
                                            const _Float16* __restrict__ U,
                                            float* __restrict__ Xw) {
    __shared__ float sbuf[4];
    int row = blockIdx.x;
    int c = threadIdx.x << 1;
    float2 v;
    if (INIT) {
        int b = row >> 10, n = row & (NN - 1);
        float m = (n < slen[b]) ? 1.0f : 0.0f;
        float2 s2 = *(const float2*)&seq[(size_t)row * 512 + c];
        float2 p2 = *(const float2*)&pos[(size_t)n * 512 + c];
        const float SD = 22.627416997969522f;
        v.x = (s2.x * SD + p2.x) * m;
        v.y = (s2.y * SD + p2.y) * m;
        *(float2*)&Xw[(size_t)row * 512 + c] = v;
    } else {
        v = *(const float2*)&X[(size_t)row * 512 + c];
        int nn = row & 1023;
        if (X2 && nn >= 384) {
            float2 v2 = *(const float2*)&X2[(size_t)row * 512 + c];
            v.x += v2.x; v.y += v2.y;
        }
        if (X3 && nn >= 768) {
            float2 v3 = *(const float2*)&X3[(size_t)row * 512 + c];
            v.x += v3.x; v.y += v3.y;
        }
    }

    float s = v.x + v.y;
    #pragma unroll
    for (int off = 1; off < 64; off <<= 1) s += __shfl_xor(s, off);
    if ((threadIdx.x & 63) == 0) sbuf[threadIdx.x >> 6] = s;
    __syncthreads();
    s = sbuf[0] + sbuf[1] + sbuf[2] + sbuf[3];
    float mu = s * (1.0f / 512.0f);
    float dx = v.x - mu, dy = v.y - mu;
    float ss = dx * dx + dy * dy;
    __syncthreads();
    #pragma unroll
    for (int off = 1; off < 64; off <<= 1) ss += __shfl_xor(ss, off);
    if ((threadIdx.x & 63) == 0) sbuf[threadIdx.x >> 6] = ss;
    __syncthreads();
    ss = sbuf[0] + sbuf[1] + sbuf[2] + sbuf[3];
    float rs = rsqrtf(ss * (1.0f / 512.0f) + 1e-6f);

    float o0 = dx * rs * g[c] + bt[c];
    float o1 = dy * rs * g[c + 1] + bt[c + 1];
    if (U) {
        o0 *= (float)U[(size_t)row * 2048 + c];
        o1 *= (float)U[(size_t)row * 2048 + c + 1];
    }
    h2 o;
    o[0] = (_Float16)o0; o[1] = (_Float16)o1;
    *(h2*)&O[(size_t)row * 512 + c] = o;
}

// ---------------------------------------------------------------- MFMA GEMM (fp16 in, f32 acc)
// WAVES waves/block; wave grid WGR x WGC over the BM x BN tile.
template<int EPI, int BM, int BN, int WAVES, int WGR, int WGC>
__global__ __launch_bounds__(WAVES * 64) void k_gemm(const _Float16* __restrict__ A,
                                                     const _Float16* __restrict__ Bm,
                                                     int K, int Ncols,
                                                     _Float16* __restrict__ Cu,
                                                     _Float16* __restrict__ vT,
                                                     const float* __restrict__ bo,
                                                     const int* __restrict__ slen,
                                                     float* __restrict__ Xio) {
    constexpr int WR = BM / WGR / 16;   // 16-row frags per wave
    constexpr int WC = BN / WGC / 16;
    constexpr int QA = BM * 8 / (WAVES * 64);   // 16B-chunk stage iters (A)
    constexpr int QB = BN * 8 / (WAVES * 64);
    __shared__ _Float16 As[2][BM * 64];
    __shared__ _Float16 Bs[2][BN * 64];
    int tid = threadIdx.x;
    int w = tid >> 6, lane = tid & 63;
    int t = lane & 15, gq = lane >> 4;
    // XCD-aware chunked swizzle (grid size % 8 == 0)
    int flat = blockIdx.y * gridDim.x + blockIdx.x;
    int cpx = (gridDim.x * gridDim.y) >> 3;
    int f2 = (flat & 7) * cpx + (flat >> 3);
    int bx = f2 % gridDim.x, by = f2 / gridDim.x;
    int row0 = by * BM, col0 = bx * BN;
    int wr = (w / WGC) * (BM / WGR), wc = (w % WGC) * (BN / WGC);

    f4 zero4 = {0.0f, 0.0f, 0.0f, 0.0f};
    f4 acc[WR][WC];
    #pragma unroll
    for (int i = 0; i < WR; ++i)
        #pragma unroll
        for (int j = 0; j < WC; ++j) acc[i][j] = zero4;

    auto stage = [&](int buf, int k0) {
        #pragma unroll
        for (int q = 0; q < QA; ++q) {
            int s = (q * WAVES + w) * 64 + lane;
            int r = s >> 3, cs = (s & 7) ^ (r & 7);
            gl16(A + (size_t)(row0 + r) * K + k0 + (cs << 3),
                 (char*)&As[buf][0] + (size_t)(q * WAVES + w) * 1024);
        }
        #pragma unroll
        for (int q = 0; q < QB; ++q) {
            int s = (q * WAVES + w) * 64 + lane;
            int r = s >> 3, cs = (s & 7) ^ (r & 7);
            gl16(Bm + (size_t)(col0 + r) * K + k0 + (cs << 3),
                 (char*)&Bs[buf][0] + (size_t)(q * WAVES + w) * 1024);
        }
    };

    stage(0, 0);
    int cur = 0;
    for (int k0 = 0; k0 < K; k0 += 64) {
        __syncthreads();
        if (k0 + 64 < K) stage(cur ^ 1, k0 + 64);
        h8 af[WR][2], bf[WC][2];
        #pragma unroll
        for (int i = 0; i < WR; ++i) {
            int rl = wr + (i << 4) + t;
            #pragma unroll
            for (int ks = 0; ks < 2; ++ks)
                af[i][ks] = *(const h8*)((const char*)&As[cur][0] + rl * 128 +
                                         (((gq + (ks << 2)) ^ (rl & 7)) << 4));
        }
        #pragma unroll
        for (int j = 0; j < WC; ++j) {
            int nl = wc + (j << 4) + t;
            #pragma unroll
            for (int ks = 0; ks < 2; ++ks)
                bf[j][ks] = *(const h8*)((const char*)&Bs[cur][0] + nl * 128 +
                                         (((gq + (ks << 2)) ^ (nl & 7)) << 4));
        }
        #pragma unroll
        for (int i = 0; i < WR; ++i)
            #pragma unroll
            for (int j = 0; j < WC; ++j) {
                acc[i][j] = __builtin_amdgcn_mfma_f32_16x16x32_f16(af[i][0], bf[j][0], acc[i][j], 0, 0, 0);
                acc[i][j] = __builtin_amdgcn_mfma_f32_16x16x32_f16(af[i][1], bf[j][1], acc[i][j], 0, 0, 0);
            }
        cur ^= 1;
    }

    #pragma unroll
    for (int i = 0; i < WR; ++i) {
        #pragma unroll
        for (int j = 0; j < WC; ++j) {
            int colf = col0 + wc + (j << 4) + t;
            int rowb = row0 + wr + (i << 4) + (gq << 2);
            if (EPI == 0) {
                if (colf >= 512 && colf < 1024) {
                    int b = rowb >> 10;
                    int hh = (colf - 512) >> 6, dd = (colf - 512) & 63;
                    h4 pk;
                    #pragma unroll
                    for (int rr = 0; rr < 4; ++rr) pk[rr] = (_Float16)fast_silu(acc[i][j][rr]);
                    size_t off = ((size_t)((b << 3) + hh) * 64 + dd) * 1024 + (rowb & 1023);
                    *(h4*)&vT[off] = pk;
                } else {
                    #pragma unroll
                    for (int rr = 0; rr < 4; ++rr)
                        Cu[(size_t)(rowb + rr) * 2048 + colf] = (_Float16)fast_silu(acc[i][j][rr]);
                }
            } else {
                int b = rowb >> 10;
                #pragma unroll
                for (int rr = 0; rr < 4; ++rr) {
                    int row = rowb + rr;
                    float m = ((row & 1023) < slen[b]) ? 1.0f : 0.0f;
                    size_t ix = (size_t)row * 512 + colf;
                    Xio[ix] = (Xio[ix] + acc[i][j][rr] + bo[colf]) * m;
                }
            }
        }
    }
}

// ---------------------------------------------------------------- fused attention (MFMA, swapped QK^T)
// 30 work-units per (b,h): nt<6 whole -> av0; nt 6..11 2-way -> av0/av1;
// nt 12..15 3-way -> av0/av1/av2. Summed in k_ln (thresholds 384/768).
__global__ __launch_bounds__(256) void k_attn(const _Float16* __restrict__ uvqk,
                                              const _Float16* __restrict__ vT,
                                              const float* __restrict__ posw,
                                              float* __restrict__ av0,
                                              float* __restrict__ av1,
                                              float* __restrict__ av2) {
    __shared__ _Float16 Ks[2][64 * 64];   // 16 KB (Ks[1] doubles as Q staging)
    __shared__ _Float16 Vs[64 * 64];      // 8 KB, single-buffered
    __shared__ _Float16 Ps[64 * 72];      // 9.2 KB, row stride 144 B
    __shared__ float pws[2][128];         // 1 KB
    int tid = threadIdx.x;
    int w = tid >> 6, lane = tid & 63;
    int t = lane & 15, gq = lane >> 4;
    int flat = blockIdx.x + 30 * (blockIdx.y + 8 * blockIdx.z);
    int f2 = (flat & 7) * 120 + (flat >> 3);
    int u = f2 % 30, h = (f2 / 30) & 7, b = f2 / 240;

    int nt, mlo, mhi;
    float* avout;
    if (u < 6) { nt = u; mlo = 0; mhi = nt; avout = av0; }
    else if (u < 18) {
        int p = u - 6; nt = 6 + (p >> 1);
        int c0 = (nt + 2) >> 1;
        if (p & 1) { mlo = c0; mhi = nt; avout = av1; }
        else       { mlo = 0;  mhi = c0 - 1; avout = av0; }
    } else {
        int p = u - 18; int third = p / 3; nt = 12 + third; int q3 = p - 3 * third;
        int c = nt + 1;
        int c1 = (c + 2) / 3, c2 = (2 * c + 2) / 3;
        if (q3 == 0)      { mlo = 0;  mhi = c1 - 1; avout = av0; }
        else if (q3 == 1) { mlo = c1; mhi = c2 - 1; avout = av1; }
        else              { mlo = c2; mhi = nt;     avout = av2; }
    }
    int n0 = nt << 6;

    const _Float16* qbase = uvqk + (size_t)b * NN * 2048 + 1024 + h * 64;
    const _Float16* kbase = uvqk + (size_t)b * NN * 2048 + 1536 + h * 64;
    const _Float16* vbase = vT + (size_t)((b << 3) + h) * 64 * 1024;

    // prologue: Q -> Ks[1], K(mlo) -> Ks[0], pws[0]
    #pragma unroll
    for (int q = 0; q < 2; ++q) {
        int s = (((w << 1) + q) << 6) + lane;
        int r = s >> 3, cs = (s & 7) ^ (r & 7);
        gl16(qbase + (size_t)(n0 + r) * 2048 + (cs << 3),
             (char*)&Ks[1][0] + (size_t)(((w << 1) + q) << 6) * 16);
        gl16(kbase + (size_t)((mlo << 6) + r) * 2048 + (cs << 3),
             (char*)&Ks[0][0] + (size_t)(((w << 1) + q) << 6) * 16);
    }
    if (tid < 128) pws[0][tid] = posw[(mlo << 6) - n0 + tid + 960];
    __syncthreads();

    h8 aq[2];
    {
        int rl = (w << 4) + t;
        #pragma unroll
        for (int ks = 0; ks < 2; ++ks)
            aq[ks] = *(const h8*)((const char*)&Ks[1][0] + rl * 128 +
                                  (((gq + (ks << 2)) ^ (rl & 7)) << 4));
    }
    asm volatile("s_waitcnt lgkmcnt(0)" ::: "memory");
    __builtin_amdgcn_sched_barrier(0);
    __syncthreads();   // all waves hold aq before Ks[1] is overwritten by prefetch

    f4 zero4 = {0.0f, 0.0f, 0.0f, 0.0f};
    f4 avacc[4];
    #pragma unroll
    for (int j = 0; j < 4; ++j) avacc[j] = zero4;

    int cur = 0;
    for (int mt = mlo; mt <= mhi; ++mt) {
        int m0 = mt << 6;
        #pragma unroll
        for (int q = 0; q < 2; ++q) {
            int s = (((w << 1) + q) << 6) + lane;
            int r = s >> 3, cs = (s & 7) ^ (r & 7);
            gl16(vbase + (size_t)r * 1024 + m0 + (cs << 3),
                 (char*)&Vs[0] + (size_t)(((w << 1) + q) << 6) * 16);
        }
        int mt2 = (mt < mhi) ? mt + 1 : mt;   // clamped: keeps vmcnt count uniform
        #pragma unroll
        for (int q = 0; q < 2; ++q) {
            int s = (((w << 1) + q) << 6) + lane;
            int r = s >> 3, cs = (s & 7) ^ (r & 7);
            gl16(kbase + (size_t)((mt2 << 6) + r) * 2048 + (cs << 3),
                 (char*)&Ks[cur ^ 1][0] + (size_t)(((w << 1) + q) << 6) * 16);
        }
        if (tid < 128) pws[cur ^ 1][tid] = posw[(mt2 << 6) - n0 + tid + 960];

        // S^T = K Q^T with rel-pos bias folded into MFMA C-in
        f4 sacc[4];
        __builtin_amdgcn_s_setprio(1);
        #pragma unroll
        for (int i = 0; i < 4; ++i) {
            f4 binit;
            #pragma unroll
            for (int rr = 0; rr < 4; ++rr)
                binit[rr] = pws[cur][63 + (i << 4) + (gq << 2) + rr - ((w << 4) + t)];
            int ml = (i << 4) + t;
            h8 ak0 = *(const h8*)((const char*)&Ks[cur][0] + ml * 128 + (((gq + 0) ^ (ml & 7)) << 4));
            h8 ak1 = *(const h8*)((const char*)&Ks[cur][0] + ml * 128 + (((gq + 4) ^ (ml & 7)) << 4));
            sacc[i] = __builtin_amdgcn_mfma_f32_16x16x32_f16(ak0, aq[0], binit, 0, 0, 0);
            sacc[i] = __builtin_amdgcn_mfma_f32_16x16x32_f16(ak1, aq[1], sacc[i], 0, 0, 0);
        }
        __builtin_amdgcn_s_setprio(0);
        // P = silu(S)*causal, packed h4 -> b64 LDS writes
        int nabs = n0 + (w << 4) + t;
        #pragma unroll
        for (int i = 0; i < 4; ++i) {
            int mb = m0 + (i << 4) + (gq << 2);
            h4 pk;
            #pragma unroll
            for (int rr = 0; rr < 4; ++rr) {
                float p = (mb + rr <= nabs) ? fast_silu(sacc[i][rr]) : 0.0f;
                pk[rr] = (_Float16)p;
            }
            *(h4*)((char*)Ps + ((w << 4) + t) * 144 + (i << 5) + (gq << 3)) = pk;
        }
        asm volatile("s_waitcnt lgkmcnt(0)" ::: "memory");  // own-wave Ps rows visible
        asm volatile("s_waitcnt vmcnt(2)" ::: "memory");    // V landed; K(next) stays in flight
        __builtin_amdgcn_s_barrier();                       // all waves' V landed
        // AV += P @ V
        __builtin_amdgcn_s_setprio(1);
        #pragma unroll
        for (int ks = 0; ks < 2; ++ks) {
            h8 pa = *(const h8*)((const char*)Ps + ((w << 4) + t) * 144 + (ks << 6) + (gq << 4));
            #pragma unroll
            for (int jt = 0; jt < 4; ++jt) {
                int dl = (jt << 4) + t;
                h8 bv = *(const h8*)((const char*)&Vs[0] + dl * 128 +
                                     (((gq + (ks << 2)) ^ (dl & 7)) << 4));
                avacc[jt] = __builtin_amdgcn_mfma_f32_16x16x32_f16(pa, bv, avacc[jt], 0, 0, 0);
            }
        }
        __builtin_amdgcn_s_setprio(0);
        __syncthreads();   // PV reads done before next-iter Vs/Ks overwrite; drains vmcnt
        cur ^= 1;
    }

    #pragma unroll
    for (int jt = 0; jt < 4; ++jt) {
        #pragma unroll
        for (int rr = 0; rr < 4; ++rr) {
            int n = n0 + (w << 4) + (gq << 2) + rr;
            int d = (jt << 4) + t;
            avout[(size_t)(b * NN + n) * 512 + h * 64 + d] = avacc[jt][rr] * (1.0f / 1024.0f);
        }
    }
}

// ---------------------------------------------------------------- final L2 norm
__global__ __launch_bounds__(256) void k_norm(float* __restrict__ X) {
    __shared__ float sbuf[4];
    int row = blockIdx.x;
    int c = threadIdx.x << 1;
    float2 v = *(const float2*)&X[(size_t)row * 512 + c];
    float ss = v.x * v.x + v.y * v.y;
    #pragma unroll
    for (int off = 1; off < 64; off <<= 1) ss += __shfl_xor(ss, off);
    if ((threadIdx.x & 63) == 0) sbuf[threadIdx.x >> 6] = ss;
    __syncthreads();
    ss = sbuf[0] + sbuf[1] + sbuf[2] + sbuf[3];
    float norm = sqrtf(ss);
    float sc = 1.0f / fmaxf(norm, 1e-6f);
    X[(size_t)row * 512 + c] = v.x * sc;
    X[(size_t)row * 512 + c + 1] = v.y * sc;
}

// ---------------------------------------------------------------- launch
extern "C" void kernel_launch(void* const* d_in, const int* in_sizes, int n_in,
                              void* d_out, int out_size, void* d_ws, size_t ws_size,
                              hipStream_t stream) {
    const float* seq   = (const float*)d_in[0];
    const int*   slen  = (const int*)d_in[1];
    const float* pos   = (const float*)d_in[2];
    const float* ln1g  = (const float*)d_in[3];
    const float* ln1b  = (const float*)d_in[4];
    const float* wuvqk = (const float*)d_in[5];
    const float* ln2g  = (const float*)d_in[6];
    const float* ln2b  = (const float*)d_in[7];
    const float* wo    = (const float*)d_in[8];
    const float* bo    = (const float*)d_in[9];
    const float* posw  = (const float*)d_in[10];

    float* x = (float*)d_out;
    char* W = (char*)d_ws;
    _Float16* nx16   = (_Float16*)(W);                       // 4 MiB
    _Float16* oin16  = (_Float16*)(W + (4u << 20));          // 4 MiB
    _Float16* uvqk16 = (_Float16*)(W + (8u << 20));          // 16 MiB
    _Float16* vT16   = (_Float16*)(W + (24u << 20));         // 4 MiB [b][h][d][n]
    float*    av0    = (float*)   (W + (28u << 20));         // 8 MiB
    float*    av1    = (float*)   (W + (36u << 20));         // 8 MiB
    float*    av2    = (float*)   (W + (44u << 20));         // 8 MiB
    _Float16* wuT16  = (_Float16*)(W + (52u << 20));         // 8 MiB [l][2048][512]
    _Float16* woT16  = (_Float16*)(W + (60u << 20));         // 2 MiB [l][512][512]

    k_transpose16<<<dim3(32, 8, 8), 256, 0, stream>>>(wuvqk, wuT16, wo, woT16);
    for (int l = 0; l < NBL; ++l) {
        if (l == 0)
            k_ln<1><<<ROWS, 256, 0, stream>>>(nullptr, nullptr, nullptr, seq, pos, slen,
                                              ln1g, ln1b, nx16, nullptr, x);
        else
            k_ln<0><<<ROWS, 256, 0, stream>>>(x, nullptr, nullptr, nullptr, nullptr, nullptr,
                                              ln1g + l * 512, ln1b + l * 512, nx16, nullptr, nullptr);
        k_gemm<0, 128, 128, 8, 2, 4><<<dim3(16, 32), 512, 0, stream>>>(
            nx16, wuT16 + (size_t)l * 2048 * 512, 512, 2048, uvqk16, vT16, nullptr, nullptr, nullptr);
        k_attn<<<dim3(30, 8, NBL), 256, 0, stream>>>(uvqk16, vT16, posw + l * (2 * NN - 1),
                                                     av0, av1, av2);
        k_ln<0><<<ROWS, 256, 0, stream>>>(av0, av1, av2, nullptr, nullptr, nullptr,
                                          ln2g + l * 512, ln2b + l * 512, oin16, uvqk16, nullptr);
        k_gemm<1, 64, 32, 4, 2, 2><<<dim3(16, 64), 256, 0, stream>>>(
            oin16, woT16 + (size_t)l * 512 * 512, 512, 512, nullptr, nullptr, bo + l * 512, slen, x);
    }
    k_norm<<<ROWS, 256, 0, stream>>>(x);
}

// Round 8
// 209.719 us; speedup vs baseline: 6.0431x; 1.1190x over previous
//
#include <hip/hip_runtime.h>
#include <math.h>
#include <stdint.h>

#define NN 1024
#define ROWS 4096
#define NBL 4

typedef _Float16 h8 __attribute__((ext_vector_type(8)));
typedef _Float16 h4 __attribute__((ext_vector_type(4)));
typedef float f4 __attribute__((ext_vector_type(4)));

__device__ __forceinline__ float fast_silu(float x) {
    float e = __builtin_amdgcn_exp2f(-1.4426950408889634f * x);
    return x * __builtin_amdgcn_rcpf(1.0f + e);
}

// async global->LDS, 16B/lane; LDS dest = wave-uniform base + lane*16
__device__ __forceinline__ void gl16(const void* gp, void* lp) {
    __builtin_amdgcn_global_load_lds(
        (const __attribute__((address_space(1))) uint32_t*)gp,
        (__attribute__((address_space(3))) uint32_t*)lp, 16, 0, 0);
}

__device__ __forceinline__ float wred(float s) {
    #pragma unroll
    for (int off = 1; off < 64; off <<= 1) s += __shfl_xor(s, off);
    return s;
}

// ---------------------------------------------------------------- transpose+fp16 convert (weights)
__global__ __launch_bounds__(256) void k_transpose16(const float* __restrict__ wuvqk,
                                                     _Float16* __restrict__ wuT,
                                                     const float* __restrict__ wo,
                                                     _Float16* __restrict__ woT) {
    __shared__ _Float16 T[64][66];
    int z = blockIdx.z;
    const float* s; _Float16* d; int N;
    if (z < 4) { N = 2048; s = wuvqk + (size_t)z * 512 * 2048; d = wuT + (size_t)z * 2048 * 512; }
    else {
        if (blockIdx.x >= 8) return;
        N = 512; s = wo + (size_t)(z - 4) * 512 * 512; d = woT + (size_t)(z - 4) * 512 * 512;
    }
    int n0 = blockIdx.x << 6, k0 = blockIdx.y << 6;
    int tx = threadIdx.x & 63, ty = threadIdx.x >> 6;
    #pragma unroll
    for (int q = 0; q < 16; ++q)
        T[(q << 2) + ty][tx] = (_Float16)s[(size_t)(k0 + (q << 2) + ty) * N + n0 + tx];
    __syncthreads();
    #pragma unroll
    for (int q = 0; q < 16; ++q)
        d[(size_t)(n0 + (q << 2) + ty) * 512 + k0 + tx] = T[tx][(q << 2) + ty];
}

// ---------------------------------------------------------------- wave-level layernorm -> fp16
// MODE 0: x -> O ; MODE 1: (seq*sqrt(D)+pos)*mask -> Xw (f32) and LN -> O ;
// MODE 2: av0(+av1 n>=384)(+av2 n>=768), LN, *U -> O
template<int MODE>
__global__ __launch_bounds__(256) void k_lnw(const float* __restrict__ X,
                                             const float* __restrict__ X2,
                                             const float* __restrict__ X3,
                                             const float* __restrict__ seq,
                                             const float* __restrict__ pos,
                                             const int* __restrict__ slen,
                                             const float* __restrict__ g,
                                             const float* __restrict__ bt,
                                             _Float16* __restrict__ O,
                                             const _Float16* __restrict__ U,
                                             float* __restrict__ Xw) {
    int tid = threadIdx.x;
    int w = tid >> 6, lane = tid & 63;
    int c = lane << 3;
    #pragma unroll
    for (int rr = 0; rr < 2; ++rr) {
        int row = (blockIdx.x << 3) + (w << 1) + rr;
        float v[8];
        if (MODE == 1) {
            int b = row >> 10, n = row & (NN - 1);
            float m = (n < slen[b]) ? 1.0f : 0.0f;
            const float4* sp = (const float4*)&seq[(size_t)row * 512 + c];
            const float4* pp = (const float4*)&pos[(size_t)n * 512 + c];
            const float SD = 22.627416997969522f;
            float4 s0 = sp[0], s1 = sp[1], p0 = pp[0], p1 = pp[1];
            v[0]=(s0.x*SD+p0.x)*m; v[1]=(s0.y*SD+p0.y)*m; v[2]=(s0.z*SD+p0.z)*m; v[3]=(s0.w*SD+p0.w)*m;
            v[4]=(s1.x*SD+p1.x)*m; v[5]=(s1.y*SD+p1.y)*m; v[6]=(s1.z*SD+p1.z)*m; v[7]=(s1.w*SD+p1.w)*m;
            float4 o0, o1;
            o0.x=v[0]; o0.y=v[1]; o0.z=v[2]; o0.w=v[3];
            o1.x=v[4]; o1.y=v[5]; o1.z=v[6]; o1.w=v[7];
            float4* xp = (float4*)&Xw[(size_t)row * 512 + c];
            xp[0] = o0; xp[1] = o1;
        } else {
            const float4* xp = (const float4*)&X[(size_t)row * 512 + c];
            float4 a = xp[0], b4 = xp[1];
            v[0]=a.x; v[1]=a.y; v[2]=a.z; v[3]=a.w; v[4]=b4.x; v[5]=b4.y; v[6]=b4.z; v[7]=b4.w;
            if (MODE == 2) {
                int nn = row & (NN - 1);
                if (nn >= 384) {
                    const float4* qp = (const float4*)&X2[(size_t)row * 512 + c];
                    float4 t0 = qp[0], t1 = qp[1];
                    v[0]+=t0.x; v[1]+=t0.y; v[2]+=t0.z; v[3]+=t0.w;
                    v[4]+=t1.x; v[5]+=t1.y; v[6]+=t1.z; v[7]+=t1.w;
                }
                if (nn >= 768) {
                    const float4* qp = (const float4*)&X3[(size_t)row * 512 + c];
                    float4 t0 = qp[0], t1 = qp[1];
                    v[0]+=t0.x; v[1]+=t0.y; v[2]+=t0.z; v[3]+=t0.w;
                    v[4]+=t1.x; v[5]+=t1.y; v[6]+=t1.z; v[7]+=t1.w;
                }
            }
        }
        float s = v[0]+v[1]+v[2]+v[3]+v[4]+v[5]+v[6]+v[7];
        s = wred(s);
        float mu = s * (1.0f / 512.0f);
        float ss = 0.0f;
        #pragma unroll
        for (int i = 0; i < 8; ++i) { float d = v[i] - mu; ss += d * d; }
        ss = wred(ss);
        float rs = rsqrtf(ss * (1.0f / 512.0f) + 1e-6f);

        const float4* gp = (const float4*)&g[c];
        const float4* bp = (const float4*)&bt[c];
        float4 g0 = gp[0], g1 = gp[1], b0 = bp[0], b1 = bp[1];
        float gg[8] = {g0.x,g0.y,g0.z,g0.w,g1.x,g1.y,g1.z,g1.w};
        float bb[8] = {b0.x,b0.y,b0.z,b0.w,b1.x,b1.y,b1.z,b1.w};
        float o[8];
        #pragma unroll
        for (int i = 0; i < 8; ++i) o[i] = (v[i] - mu) * rs * gg[i] + bb[i];
        if (MODE == 2) {
            h8 uu = *(const h8*)&U[(size_t)row * 2048 + c];
            #pragma unroll
            for (int i = 0; i < 8; ++i) o[i] *= (float)uu[i];
        }
        h8 oh;
        #pragma unroll
        for (int i = 0; i < 8; ++i) oh[i] = (_Float16)o[i];
        *(h8*)&O[(size_t)row * 512 + c] = oh;
    }
}

// ---------------------------------------------------------------- final L2 norm (wave/row)
__global__ __launch_bounds__(256) void k_normw(float* __restrict__ X) {
    int tid = threadIdx.x;
    int w = tid >> 6, lane = tid & 63;
    int c = lane << 3;
    #pragma unroll
    for (int rr = 0; rr < 2; ++rr) {
        int row = (blockIdx.x << 3) + (w << 1) + rr;
        float4* xp = (float4*)&X[(size_t)row * 512 + c];
        float4 a = xp[0], b4 = xp[1];
        float ss = a.x*a.x + a.y*a.y + a.z*a.z + a.w*a.w +
                   b4.x*b4.x + b4.y*b4.y + b4.z*b4.z + b4.w*b4.w;
        ss = wred(ss);
        float sc = 1.0f / fmaxf(sqrtf(ss), 1e-6f);
        a.x*=sc; a.y*=sc; a.z*=sc; a.w*=sc; b4.x*=sc; b4.y*=sc; b4.z*=sc; b4.w*=sc;
        xp[0] = a; xp[1] = b4;
    }
}

// ---------------------------------------------------------------- MFMA GEMM (fp16 in, f32 acc)
// EPI 0 (uvqk): LDS-staged epilogue, coalesced h8 stores; v-blocks transposed -> vT
// EPI 1: X = (X + C + bo) * mask
template<int EPI, int BM, int BN, int WAVES, int WGR, int WGC>
__global__ __launch_bounds__(WAVES * 64) void k_gemm(const _Float16* __restrict__ A,
                                                     const _Float16* __restrict__ Bm,
                                                     _Float16* __restrict__ Cu,
                                                     _Float16* __restrict__ vT,
                                                     const float* __restrict__ bo,
                                                     const int* __restrict__ slen,
                                                     float* __restrict__ Xio) {
    constexpr int WR = BM / WGR / 16;
    constexpr int WC = BN / WGC / 16;
    constexpr int QA = BM * 8 / (WAVES * 64);
    constexpr int QB = BN * 8 / (WAVES * 64);
    __shared__ _Float16 smem[2 * 64 * (BM + BN)];
    _Float16* AsB = smem;                    // [2][BM*64]
    _Float16* BsB = smem + 2 * BM * 64;      // [2][BN*64]
    int tid = threadIdx.x;
    int w = tid >> 6, lane = tid & 63;
    int t = lane & 15, gq = lane >> 4;
    int flat = blockIdx.y * gridDim.x + blockIdx.x;
    int cpx = (gridDim.x * gridDim.y) >> 3;
    int f2 = (flat & 7) * cpx + (flat >> 3);
    int bx = f2 % gridDim.x, by = f2 / gridDim.x;
    int row0 = by * BM, col0 = bx * BN;
    int wr = (w / WGC) * (BM / WGR), wc = (w % WGC) * (BN / WGC);

    f4 zero4 = {0.0f, 0.0f, 0.0f, 0.0f};
    f4 acc[WR][WC];
    #pragma unroll
    for (int i = 0; i < WR; ++i)
        #pragma unroll
        for (int j = 0; j < WC; ++j) acc[i][j] = zero4;

    auto stage = [&](int buf, int k0) {
        _Float16* As = AsB + buf * BM * 64;
        _Float16* Bs = BsB + buf * BN * 64;
        #pragma unroll
        for (int q = 0; q < QA; ++q) {
            int s = (q * WAVES + w) * 64 + lane;
            int r = s >> 3, cs = (s & 7) ^ (r & 7);
            gl16(A + (size_t)(row0 + r) * 512 + k0 + (cs << 3),
                 (char*)As + (size_t)(q * WAVES + w) * 1024);
        }
        #pragma unroll
        for (int q = 0; q < QB; ++q) {
            int s = (q * WAVES + w) * 64 + lane;
            int r = s >> 3, cs = (s & 7) ^ (r & 7);
            gl16(Bm + (size_t)(col0 + r) * 512 + k0 + (cs << 3),
                 (char*)Bs + (size_t)(q * WAVES + w) * 1024);
        }
    };

    stage(0, 0);
    int cur = 0;
    for (int k0 = 0; k0 < 512; k0 += 64) {
        __syncthreads();
        if (k0 + 64 < 512) stage(cur ^ 1, k0 + 64);
        const char* As = (const char*)(AsB + cur * BM * 64);
        const char* Bs = (const char*)(BsB + cur * BN * 64);
        h8 af[WR][2], bf[WC][2];
        #pragma unroll
        for (int i = 0; i < WR; ++i) {
            int rl = wr + (i << 4) + t;
            #pragma unroll
            for (int ks = 0; ks < 2; ++ks)
                af[i][ks] = *(const h8*)(As + rl * 128 + (((gq + (ks << 2)) ^ (rl & 7)) << 4));
        }
        #pragma unroll
        for (int j = 0; j < WC; ++j) {
            int nl = wc + (j << 4) + t;
            #pragma unroll
            for (int ks = 0; ks < 2; ++ks)
                bf[j][ks] = *(const h8*)(Bs + nl * 128 + (((gq + (ks << 2)) ^ (nl & 7)) << 4));
        }
        #pragma unroll
        for (int i = 0; i < WR; ++i)
            #pragma unroll
            for (int j = 0; j < WC; ++j) {
                acc[i][j] = __builtin_amdgcn_mfma_f32_16x16x32_f16(af[i][0], bf[j][0], acc[i][j], 0, 0, 0);
                acc[i][j] = __builtin_amdgcn_mfma_f32_16x16x32_f16(af[i][1], bf[j][1], acc[i][j], 0, 0, 0);
            }
        cur ^= 1;
    }

    if (EPI == 0) {
        // LDS-staged epilogue: E stride 136 h2; v-blocks stored transposed
        _Float16* E = smem;   // 128*136 h2 = 34816 B <= 64 KB
        bool vblk = (col0 >= 512 && col0 < 1024);
        __syncthreads();   // all MFMA LDS reads done
        if (vblk) {
            #pragma unroll
            for (int i = 0; i < WR; ++i)
                #pragma unroll
                for (int j = 0; j < WC; ++j) {
                    int cl = wc + (j << 4) + t;
                    int rl = wr + (i << 4) + (gq << 2);
                    h4 pk;
                    #pragma unroll
                    for (int rr = 0; rr < 4; ++rr) pk[rr] = (_Float16)fast_silu(acc[i][j][rr]);
                    *(h4*)&E[cl * 136 + rl] = pk;   // E_T[d][n]
                }
        } else {
            #pragma unroll
            for (int i = 0; i < WR; ++i)
                #pragma unroll
                for (int j = 0; j < WC; ++j) {
                    int cl = wc + (j << 4) + t;
                    int rl = wr + (i << 4) + (gq << 2);
                    #pragma unroll
                    for (int rr = 0; rr < 4; ++rr)
                        E[(rl + rr) * 136 + cl] = (_Float16)fast_silu(acc[i][j][rr]);
                }
        }
        __syncthreads();
        constexpr int ITERS = 128 * 16 / (WAVES * 64);
        if (vblk) {
            int b = row0 >> 10;
            int n0l = row0 & 1023;
            #pragma unroll
            for (int it = 0; it < ITERS; ++it) {
                int dl = it * (WAVES * 4) + (tid >> 4);
                int cc = tid & 15;
                h8 vv = *(const h8*)&E[dl * 136 + (cc << 3)];
                int hh = (col0 + dl - 512) >> 6, dd = (col0 + dl - 512) & 63;
                *(h8*)&vT[((size_t)((b << 3) + hh) * 64 + dd) * 1024 + n0l + (cc << 3)] = vv;
            }
        } else {
            #pragma unroll
            for (int it = 0; it < ITERS; ++it) {
                int rl = it * (WAVES * 4) + (tid >> 4);
                int cc = tid & 15;
                h8 vv = *(const h8*)&E[rl * 136 + (cc << 3)];
                *(h8*)&Cu[(size_t)(row0 + rl) * 2048 + col0 + (cc << 3)] = vv;
            }
        }
    } else {
        #pragma unroll
        for (int i = 0; i < WR; ++i) {
            #pragma unroll
            for (int j = 0; j < WC; ++j) {
                int colf = col0 + wc + (j << 4) + t;
                int rowb = row0 + wr + (i << 4) + (gq << 2);
                int b = rowb >> 10;
                #pragma unroll
                for (int rr = 0; rr < 4; ++rr) {
                    int row = rowb + rr;
                    float m = ((row & 1023) < slen[b]) ? 1.0f : 0.0f;
                    size_t ix = (size_t)row * 512 + colf;
                    Xio[ix] = (Xio[ix] + acc[i][j][rr] + bo[colf]) * m;
                }
            }
        }
    }
}

// ---------------------------------------------------------------- fused attention (MFMA, swapped QK^T)
__global__ __launch_bounds__(256) void k_attn(const _Float16* __restrict__ uvqk,
                                              const _Float16* __restrict__ vT,
                                              const float* __restrict__ posw,
                                              float* __restrict__ av0,
                                              float* __restrict__ av1,
                                              float* __restrict__ av2) {
    __shared__ _Float16 Ks[2][64 * 64];
    __shared__ _Float16 Vs[64 * 64];
    __shared__ _Float16 Ps[64 * 72];
    __shared__ float pws[2][128];
    int tid = threadIdx.x;
    int w = tid >> 6, lane = tid & 63;
    int t = lane & 15, gq = lane >> 4;
    int flat = blockIdx.x + 30 * (blockIdx.y + 8 * blockIdx.z);
    int f2 = (flat & 7) * 120 + (flat >> 3);
    int u = f2 % 30, h = (f2 / 30) & 7, b = f2 / 240;

    int nt, mlo, mhi;
    float* avout;
    if (u < 6) { nt = u; mlo = 0; mhi = nt; avout = av0; }
    else if (u < 18) {
        int p = u - 6; nt = 6 + (p >> 1);
        int c0 = (nt + 2) >> 1;
        if (p & 1) { mlo = c0; mhi = nt; avout = av1; }
        else       { mlo = 0;  mhi = c0 - 1; avout = av0; }
    } else {
        int p = u - 18; int third = p / 3; nt = 12 + third; int q3 = p - 3 * third;
        int c = nt + 1, c1 = (c + 2) / 3, c2 = (2 * c + 2) / 3;
        if (q3 == 0)      { mlo = 0;  mhi = c1 - 1; avout = av0; }
        else if (q3 == 1) { mlo = c1; mhi = c2 - 1; avout = av1; }
        else              { mlo = c2; mhi = nt;     avout = av2; }
    }
    int n0 = nt << 6;

    const _Float16* qbase = uvqk + (size_t)b * NN * 2048 + 1024 + h * 64;
    const _Float16* kbase = uvqk + (size_t)b * NN * 2048 + 1536 + h * 64;
    const _Float16* vbase = vT + (size_t)((b << 3) + h) * 64 * 1024;

    #pragma unroll
    for (int q = 0; q < 2; ++q) {
        int s = (((w << 1) + q) << 6) + lane;
        int r = s >> 3, cs = (s & 7) ^ (r & 7);
        gl16(qbase + (size_t)(n0 + r) * 2048 + (cs << 3),
             (char*)&Ks[1][0] + (size_t)(((w << 1) + q) << 6) * 16);
        gl16(kbase + (size_t)((mlo << 6) + r) * 2048 + (cs << 3),
             (char*)&Ks[0][0] + (size_t)(((w << 1) + q) << 6) * 16);
    }
    if (tid < 128) pws[0][tid] = posw[(mlo << 6) - n0 + tid + 960];
    __syncthreads();

    h8 aq[2];
    {
        int rl = (w << 4) + t;
        #pragma unroll
        for (int ks = 0; ks < 2; ++ks)
            aq[ks] = *(const h8*)((const char*)&Ks[1][0] + rl * 128 +
                                  (((gq + (ks << 2)) ^ (rl & 7)) << 4));
    }
    asm volatile("s_waitcnt lgkmcnt(0)" ::: "memory");
    __builtin_amdgcn_sched_barrier(0);
    __syncthreads();

    f4 zero4 = {0.0f, 0.0f, 0.0f, 0.0f};
    f4 avacc[4];
    #pragma unroll
    for (int j = 0; j < 4; ++j) avacc[j] = zero4;

    int cur = 0;
    for (int mt = mlo; mt <= mhi; ++mt) {
        int m0 = mt << 6;
        #pragma unroll
        for (int q = 0; q < 2; ++q) {
            int s = (((w << 1) + q) << 6) + lane;
            int r = s >> 3, cs = (s & 7) ^ (r & 7);
            gl16(vbase + (size_t)r * 1024 + m0 + (cs << 3),
                 (char*)&Vs[0] + (size_t)(((w << 1) + q) << 6) * 16);
        }
        int mt2 = (mt < mhi) ? mt + 1 : mt;
        #pragma unroll
        for (int q = 0; q < 2; ++q) {
            int s = (((w << 1) + q) << 6) + lane;
            int r = s >> 3, cs = (s & 7) ^ (r & 7);
            gl16(kbase + (size_t)((mt2 << 6) + r) * 2048 + (cs << 3),
                 (char*)&Ks[cur ^ 1][0] + (size_t)(((w << 1) + q) << 6) * 16);
        }
        if (tid < 128) pws[cur ^ 1][tid] = posw[(mt2 << 6) - n0 + tid + 960];

        f4 sacc[4];
        __builtin_amdgcn_s_setprio(1);
        #pragma unroll
        for (int i = 0; i < 4; ++i) {
            f4 binit;
            #pragma unroll
            for (int rr = 0; rr < 4; ++rr)
                binit[rr] = pws[cur][63 + (i << 4) + (gq << 2) + rr - ((w << 4) + t)];
            int ml = (i << 4) + t;
            h8 ak0 = *(const h8*)((const char*)&Ks[cur][0] + ml * 128 + (((gq + 0) ^ (ml & 7)) << 4));
            h8 ak1 = *(const h8*)((const char*)&Ks[cur][0] + ml * 128 + (((gq + 4) ^ (ml & 7)) << 4));
            sacc[i] = __builtin_amdgcn_mfma_f32_16x16x32_f16(ak0, aq[0], binit, 0, 0, 0);
            sacc[i] = __builtin_amdgcn_mfma_f32_16x16x32_f16(ak1, aq[1], sacc[i], 0, 0, 0);
        }
        __builtin_amdgcn_s_setprio(0);
        int nabs = n0 + (w << 4) + t;
        #pragma unroll
        for (int i = 0; i < 4; ++i) {
            int mb = m0 + (i << 4) + (gq << 2);
            h4 pk;
            #pragma unroll
            for (int rr = 0; rr < 4; ++rr) {
                float p = (mb + rr <= nabs) ? fast_silu(sacc[i][rr]) : 0.0f;
                pk[rr] = (_Float16)p;
            }
            *(h4*)((char*)Ps + ((w << 4) + t) * 144 + (i << 5) + (gq << 3)) = pk;
        }
        asm volatile("s_waitcnt lgkmcnt(0)" ::: "memory");
        asm volatile("s_waitcnt vmcnt(2)" ::: "memory");
        __builtin_amdgcn_s_barrier();
        __builtin_amdgcn_s_setprio(1);
        #pragma unroll
        for (int ks = 0; ks < 2; ++ks) {
            h8 pa = *(const h8*)((const char*)Ps + ((w << 4) + t) * 144 + (ks << 6) + (gq << 4));
            #pragma unroll
            for (int jt = 0; jt < 4; ++jt) {
                int dl = (jt << 4) + t;
                h8 bv = *(const h8*)((const char*)&Vs[0] + dl * 128 +
                                     (((gq + (ks << 2)) ^ (dl & 7)) << 4));
                avacc[jt] = __builtin_amdgcn_mfma_f32_16x16x32_f16(pa, bv, avacc[jt], 0, 0, 0);
            }
        }
        __builtin_amdgcn_s_setprio(0);
        __syncthreads();
        cur ^= 1;
    }

    #pragma unroll
    for (int jt = 0; jt < 4; ++jt) {
        #pragma unroll
        for (int rr = 0; rr < 4; ++rr) {
            int n = n0 + (w << 4) + (gq << 2) + rr;
            int d = (jt << 4) + t;
            avout[(size_t)(b * NN + n) * 512 + h * 64 + d] = avacc[jt][rr] * (1.0f / 1024.0f);
        }
    }
}

// ---------------------------------------------------------------- launch
extern "C" void kernel_launch(void* const* d_in, const int* in_sizes, int n_in,
                              void* d_out, int out_size, void* d_ws, size_t ws_size,
                              hipStream_t stream) {
    const float* seq   = (const float*)d_in[0];
    const int*   slen  = (const int*)d_in[1];
    const float* pos   = (const float*)d_in[2];
    const float* ln1g  = (const float*)d_in[3];
    const float* ln1b  = (const float*)d_in[4];
    const float* wuvqk = (const float*)d_in[5];
    const float* ln2g  = (const float*)d_in[6];
    const float* ln2b  = (const float*)d_in[7];
    const float* wo    = (const float*)d_in[8];
    const float* bo    = (const float*)d_in[9];
    const float* posw  = (const float*)d_in[10];

    float* x = (float*)d_out;
    char* W = (char*)d_ws;
    _Float16* nx16   = (_Float16*)(W);                       // 4 MiB
    _Float16* oin16  = (_Float16*)(W + (4u << 20));          // 4 MiB
    _Float16* uvqk16 = (_Float16*)(W + (8u << 20));          // 16 MiB
    _Float16* vT16   = (_Float16*)(W + (24u << 20));         // 4 MiB [b][h][d][n]
    float*    av0    = (float*)   (W + (28u << 20));         // 8 MiB
    float*    av1    = (float*)   (W + (36u << 20));         // 8 MiB
    float*    av2    = (float*)   (W + (44u << 20));         // 8 MiB
    _Float16* wuT16  = (_Float16*)(W + (52u << 20));         // 8 MiB [l][2048][512]
    _Float16* woT16  = (_Float16*)(W + (60u << 20));         // 2 MiB [l][512][512]

    k_transpose16<<<dim3(32, 8, 8), 256, 0, stream>>>(wuvqk, wuT16, wo, woT16);
    for (int l = 0; l < NBL; ++l) {
        if (l == 0)
            k_lnw<1><<<512, 256, 0, stream>>>(nullptr, nullptr, nullptr, seq, pos, slen,
                                              ln1g, ln1b, nx16, nullptr, x);
        else
            k_lnw<0><<<512, 256, 0, stream>>>(x, nullptr, nullptr, nullptr, nullptr, nullptr,
                                              ln1g + l * 512, ln1b + l * 512, nx16, nullptr, nullptr);
        k_gemm<0, 128, 128, 8, 2, 4><<<dim3(16, 32), 512, 0, stream>>>(
            nx16, wuT16 + (size_t)l * 2048 * 512, uvqk16, vT16, nullptr, nullptr, nullptr);
        k_attn<<<dim3(30, 8, NBL), 256, 0, stream>>>(uvqk16, vT16, posw + l * (2 * NN - 1),
                                                     av0, av1, av2);
        k_lnw<2><<<512, 256, 0, stream>>>(av0, av1, av2, nullptr, nullptr, nullptr,
                                          ln2g + l * 512, ln2b + l * 512, oin16, uvqk16, nullptr);
        k_gemm<1, 64, 32, 4, 2, 2><<<dim3(16, 64), 256, 0, stream>>>(
            oin16, woT16 + (size_t)l * 512 * 512, nullptr, nullptr, bo + l * 512, slen, x);
    }
    k_normw<<<512, 256, 0, stream>>>(x);
}

// Round 9
// 208.998 us; speedup vs baseline: 6.0640x; 1.0035x over previous
//
#include <hip/hip_runtime.h>
#include <hip/hip_cooperative_groups.h>
#include <math.h>
#include <stdint.h>

namespace cg = cooperative_groups;

#define NN 1024
#define ROWS 4096
#define NBL 4

typedef _Float16 h8 __attribute__((ext_vector_type(8)));
typedef _Float16 h4 __attribute__((ext_vector_type(4)));
typedef float f4 __attribute__((ext_vector_type(4)));

__device__ __forceinline__ float fast_silu(float x) {
    float e = __builtin_amdgcn_exp2f(-1.4426950408889634f * x);
    return x * __builtin_amdgcn_rcpf(1.0f + e);
}

// async global->LDS, 16B/lane; LDS dest = wave-uniform base + lane*16
__device__ __forceinline__ void gl16(const void* gp, void* lp) {
    __builtin_amdgcn_global_load_lds(
        (const __attribute__((address_space(1))) uint32_t*)gp,
        (__attribute__((address_space(3))) uint32_t*)lp, 16, 0, 0);
}

__device__ __forceinline__ float wred(float s) {
    #pragma unroll
    for (int off = 1; off < 64; off <<= 1) s += __shfl_xor(s, off);
    return s;
}

// attn units ordered by descending tile-step count (heaviest first)
__constant__ int c_order[30] = {5,14,16,17,27, 4,10,12,13,15,18,21,22,24,25,26,28,29,
                                3,6,8,9,11,19,20,23, 2,7, 1, 0};

// ================================================================ device units
// ---------------------------------------------------------------- transpose+fp16 (weights)
__device__ void transpose_unit(int u, char* smem,
                               const float* __restrict__ wuvqk, _Float16* __restrict__ wuT,
                               const float* __restrict__ wo, _Float16* __restrict__ woT) {
    _Float16 (*T)[66] = (_Float16 (*)[66])smem;
    const float* s; _Float16* d; int N, n0, k0;
    if (u < 1024) {
        int z = u >> 8, t = u & 255;
        N = 2048; s = wuvqk + (size_t)z * 512 * 2048; d = wuT + (size_t)z * 2048 * 512;
        n0 = (t & 31) << 6; k0 = (t >> 5) << 6;
    } else {
        int r2 = u - 1024; int z = r2 >> 6, t = r2 & 63;
        N = 512; s = wo + (size_t)z * 512 * 512; d = woT + (size_t)z * 512 * 512;
        n0 = (t & 7) << 6; k0 = (t >> 3) << 6;
    }
    int tid = threadIdx.x, tx = tid & 63, ty = tid >> 6;
    __syncthreads();   // LDS reuse guard (sequential units)
    #pragma unroll
    for (int q = 0; q < 16; ++q)
        T[(q << 2) + ty][tx] = (_Float16)s[(size_t)(k0 + (q << 2) + ty) * N + n0 + tx];
    __syncthreads();
    #pragma unroll
    for (int q = 0; q < 16; ++q)
        d[(size_t)(n0 + (q << 2) + ty) * 512 + k0 + tx] = T[tx][(q << 2) + ty];
}

// ---------------------------------------------------------------- wave-level layernorm -> fp16
// MODE 0: X -> O ; MODE 1: (seq*sqrt(D)+pos)*mask -> Xw and LN -> O ;
// MODE 2: X(+X2 n>=384)(+X3 n>=768), LN, *U -> O
template<int MODE>
__device__ void ln_unit(int vb,
                        const float* __restrict__ X, const float* __restrict__ X2,
                        const float* __restrict__ X3, const float* __restrict__ seq,
                        const float* __restrict__ pos, const int* __restrict__ slen,
                        const float* __restrict__ g, const float* __restrict__ bt,
                        _Float16* __restrict__ O, const _Float16* __restrict__ U,
                        float* __restrict__ Xw) {
    int tid = threadIdx.x;
    int w = tid >> 6, lane = tid & 63;
    int c = lane << 3;
    #pragma unroll
    for (int rr = 0; rr < 2; ++rr) {
        int row = (vb << 3) + (w << 1) + rr;
        float v[8];
        if (MODE == 1) {
            int b = row >> 10, n = row & (NN - 1);
            float m = (n < slen[b]) ? 1.0f : 0.0f;
            const float4* sp = (const float4*)&seq[(size_t)row * 512 + c];
            const float4* pp = (const float4*)&pos[(size_t)n * 512 + c];
            const float SD = 22.627416997969522f;
            float4 s0 = sp[0], s1 = sp[1], p0 = pp[0], p1 = pp[1];
            v[0]=(s0.x*SD+p0.x)*m; v[1]=(s0.y*SD+p0.y)*m; v[2]=(s0.z*SD+p0.z)*m; v[3]=(s0.w*SD+p0.w)*m;
            v[4]=(s1.x*SD+p1.x)*m; v[5]=(s1.y*SD+p1.y)*m; v[6]=(s1.z*SD+p1.z)*m; v[7]=(s1.w*SD+p1.w)*m;
            float4 o0, o1;
            o0.x=v[0]; o0.y=v[1]; o0.z=v[2]; o0.w=v[3];
            o1.x=v[4]; o1.y=v[5]; o1.z=v[6]; o1.w=v[7];
            float4* xp = (float4*)&Xw[(size_t)row * 512 + c];
            xp[0] = o0; xp[1] = o1;
        } else {
            const float4* xp = (const float4*)&X[(size_t)row * 512 + c];
            float4 a = xp[0], b4 = xp[1];
            v[0]=a.x; v[1]=a.y; v[2]=a.z; v[3]=a.w; v[4]=b4.x; v[5]=b4.y; v[6]=b4.z; v[7]=b4.w;
            if (MODE == 2) {
                int nn = row & (NN - 1);
                if (nn >= 384) {
                    const float4* qp = (const float4*)&X2[(size_t)row * 512 + c];
                    float4 t0 = qp[0], t1 = qp[1];
                    v[0]+=t0.x; v[1]+=t0.y; v[2]+=t0.z; v[3]+=t0.w;
                    v[4]+=t1.x; v[5]+=t1.y; v[6]+=t1.z; v[7]+=t1.w;
                }
                if (nn >= 768) {
                    const float4* qp = (const float4*)&X3[(size_t)row * 512 + c];
                    float4 t0 = qp[0], t1 = qp[1];
                    v[0]+=t0.x; v[1]+=t0.y; v[2]+=t0.z; v[3]+=t0.w;
                    v[4]+=t1.x; v[5]+=t1.y; v[6]+=t1.z; v[7]+=t1.w;
                }
            }
        }
        float s = v[0]+v[1]+v[2]+v[3]+v[4]+v[5]+v[6]+v[7];
        s = wred(s);
        float mu = s * (1.0f / 512.0f);
        float ss = 0.0f;
        #pragma unroll
        for (int i = 0; i < 8; ++i) { float d = v[i] - mu; ss += d * d; }
        ss = wred(ss);
        float rs = rsqrtf(ss * (1.0f / 512.0f) + 1e-6f);

        const float4* gp = (const float4*)&g[c];
        const float4* bp = (const float4*)&bt[c];
        float4 g0 = gp[0], g1 = gp[1], b0 = bp[0], b1 = bp[1];
        float gg[8] = {g0.x,g0.y,g0.z,g0.w,g1.x,g1.y,g1.z,g1.w};
        float bb[8] = {b0.x,b0.y,b0.z,b0.w,b1.x,b1.y,b1.z,b1.w};
        float o[8];
        #pragma unroll
        for (int i = 0; i < 8; ++i) o[i] = (v[i] - mu) * rs * gg[i] + bb[i];
        if (MODE == 2) {
            h8 uu = *(const h8*)&U[(size_t)row * 2048 + c];
            #pragma unroll
            for (int i = 0; i < 8; ++i) o[i] *= (float)uu[i];
        }
        h8 oh;
        #pragma unroll
        for (int i = 0; i < 8; ++i) oh[i] = (_Float16)o[i];
        *(h8*)&O[(size_t)row * 512 + c] = oh;
    }
}

__device__ void norm_unit(int vb, float* __restrict__ X) {
    int tid = threadIdx.x;
    int w = tid >> 6, lane = tid & 63;
    int c = lane << 3;
    #pragma unroll
    for (int rr = 0; rr < 2; ++rr) {
        int row = (vb << 3) + (w << 1) + rr;
        float4* xp = (float4*)&X[(size_t)row * 512 + c];
        float4 a = xp[0], b4 = xp[1];
        float ss = a.x*a.x + a.y*a.y + a.z*a.z + a.w*a.w +
                   b4.x*b4.x + b4.y*b4.y + b4.z*b4.z + b4.w*b4.w;
        ss = wred(ss);
        float sc = 1.0f / fmaxf(sqrtf(ss), 1e-6f);
        a.x*=sc; a.y*=sc; a.z*=sc; a.w*=sc; b4.x*=sc; b4.y*=sc; b4.z*=sc; b4.w*=sc;
        xp[0] = a; xp[1] = b4;
    }
}

// ---------------------------------------------------------------- MFMA GEMM unit
template<int EPI, int BM, int BN, int WAVES, int WGR, int WGC>
__device__ void gemm_unit(int unit, int nbx, int nunits, char* smemc,
                          const _Float16* __restrict__ A, const _Float16* __restrict__ Bm,
                          _Float16* __restrict__ Cu, _Float16* __restrict__ vT,
                          const float* __restrict__ bo, const int* __restrict__ slen,
                          float* __restrict__ Xio) {
    constexpr int WR = BM / WGR / 16;
    constexpr int WC = BN / WGC / 16;
    constexpr int QA = BM * 8 / (WAVES * 64);
    constexpr int QB = BN * 8 / (WAVES * 64);
    _Float16* AsB = (_Float16*)smemc;            // [2][BM*64]
    _Float16* BsB = (_Float16*)smemc + 2 * BM * 64;
    int tid = threadIdx.x;
    int w = tid >> 6, lane = tid & 63;
    int t = lane & 15, gq = lane >> 4;
    int cpx = nunits >> 3;
    int f2 = (unit & 7) * cpx + (unit >> 3);
    int bx = f2 % nbx, by = f2 / nbx;
    int row0 = by * BM, col0 = bx * BN;
    int wr = (w / WGC) * (BM / WGR), wc = (w % WGC) * (BN / WGC);

    __syncthreads();   // LDS reuse guard (sequential units / prior phase)

    f4 zero4 = {0.0f, 0.0f, 0.0f, 0.0f};
    f4 acc[WR][WC];
    #pragma unroll
    for (int i = 0; i < WR; ++i)
        #pragma unroll
        for (int j = 0; j < WC; ++j) acc[i][j] = zero4;

    auto stage = [&](int buf, int k0) {
        _Float16* As = AsB + buf * BM * 64;
        _Float16* Bs = BsB + buf * BN * 64;
        #pragma unroll
        for (int q = 0; q < QA; ++q) {
            int s = (q * WAVES + w) * 64 + lane;
            int r = s >> 3, cs = (s & 7) ^ (r & 7);
            gl16(A + (size_t)(row0 + r) * 512 + k0 + (cs << 3),
                 (char*)As + (size_t)(q * WAVES + w) * 1024);
        }
        #pragma unroll
        for (int q = 0; q < QB; ++q) {
            int s = (q * WAVES + w) * 64 + lane;
            int r = s >> 3, cs = (s & 7) ^ (r & 7);
            gl16(Bm + (size_t)(col0 + r) * 512 + k0 + (cs << 3),
                 (char*)Bs + (size_t)(q * WAVES + w) * 1024);
        }
    };

    stage(0, 0);
    int cur = 0;
    for (int k0 = 0; k0 < 512; k0 += 64) {
        __syncthreads();
        if (k0 + 64 < 512) stage(cur ^ 1, k0 + 64);
        const char* As = (const char*)(AsB + cur * BM * 64);
        const char* Bs = (const char*)(BsB + cur * BN * 64);
        h8 af[WR][2], bf[WC][2];
        #pragma unroll
        for (int i = 0; i < WR; ++i) {
            int rl = wr + (i << 4) + t;
            #pragma unroll
            for (int ks = 0; ks < 2; ++ks)
                af[i][ks] = *(const h8*)(As + rl * 128 + (((gq + (ks << 2)) ^ (rl & 7)) << 4));
        }
        #pragma unroll
        for (int j = 0; j < WC; ++j) {
            int nl = wc + (j << 4) + t;
            #pragma unroll
            for (int ks = 0; ks < 2; ++ks)
                bf[j][ks] = *(const h8*)(Bs + nl * 128 + (((gq + (ks << 2)) ^ (nl & 7)) << 4));
        }
        #pragma unroll
        for (int i = 0; i < WR; ++i)
            #pragma unroll
            for (int j = 0; j < WC; ++j) {
                acc[i][j] = __builtin_amdgcn_mfma_f32_16x16x32_f16(af[i][0], bf[j][0], acc[i][j], 0, 0, 0);
                acc[i][j] = __builtin_amdgcn_mfma_f32_16x16x32_f16(af[i][1], bf[j][1], acc[i][j], 0, 0, 0);
            }
        cur ^= 1;
    }

    if (EPI == 0) {
        // LDS-staged epilogue: E stride 136 h2; v-blocks stored transposed
        _Float16* E = (_Float16*)smemc;   // 128*136 h2 = 34816 B
        bool vblk = (col0 >= 512 && col0 < 1024);
        __syncthreads();
        if (vblk) {
            #pragma unroll
            for (int i = 0; i < WR; ++i)
                #pragma unroll
                for (int j = 0; j < WC; ++j) {
                    int cl = wc + (j << 4) + t;
                    int rl = wr + (i << 4) + (gq << 2);
                    h4 pk;
                    #pragma unroll
                    for (int rr = 0; rr < 4; ++rr) pk[rr] = (_Float16)fast_silu(acc[i][j][rr]);
                    *(h4*)&E[cl * 136 + rl] = pk;   // E_T[d][n]
                }
        } else {
            #pragma unroll
            for (int i = 0; i < WR; ++i)
                #pragma unroll
                for (int j = 0; j < WC; ++j) {
                    int cl = wc + (j << 4) + t;
                    int rl = wr + (i << 4) + (gq << 2);
                    #pragma unroll
                    for (int rr = 0; rr < 4; ++rr)
                        E[(rl + rr) * 136 + cl] = (_Float16)fast_silu(acc[i][j][rr]);
                }
        }
        __syncthreads();
        constexpr int ITERS = 128 * 16 / (WAVES * 64);
        if (vblk) {
            int b = row0 >> 10;
            int n0l = row0 & 1023;
            #pragma unroll
            for (int it = 0; it < ITERS; ++it) {
                int dl = it * (WAVES * 4) + (tid >> 4);
                int cc = tid & 15;
                h8 vv = *(const h8*)&E[dl * 136 + (cc << 3)];
                int hh = (col0 + dl - 512) >> 6, dd = (col0 + dl - 512) & 63;
                *(h8*)&vT[((size_t)((b << 3) + hh) * 64 + dd) * 1024 + n0l + (cc << 3)] = vv;
            }
        } else {
            #pragma unroll
            for (int it = 0; it < ITERS; ++it) {
                int rl = it * (WAVES * 4) + (tid >> 4);
                int cc = tid & 15;
                h8 vv = *(const h8*)&E[rl * 136 + (cc << 3)];
                *(h8*)&Cu[(size_t)(row0 + rl) * 2048 + col0 + (cc << 3)] = vv;
            }
        }
    } else {
        #pragma unroll
        for (int i = 0; i < WR; ++i) {
            #pragma unroll
            for (int j = 0; j < WC; ++j) {
                int colf = col0 + wc + (j << 4) + t;
                int rowb = row0 + wr + (i << 4) + (gq << 2);
                int b = rowb >> 10;
                #pragma unroll
                for (int rr = 0; rr < 4; ++rr) {
                    int row = rowb + rr;
                    float m = ((row & 1023) < slen[b]) ? 1.0f : 0.0f;
                    size_t ix = (size_t)row * 512 + colf;
                    Xio[ix] = (Xio[ix] + acc[i][j][rr] + bo[colf]) * m;
                }
            }
        }
    }
}

// ---------------------------------------------------------------- fused attention unit
__device__ void attn_unit(int b, int h, int u, char* smem,
                          const _Float16* __restrict__ uvqk, const _Float16* __restrict__ vTg,
                          const float* __restrict__ pw,
                          float* __restrict__ av0, float* __restrict__ av1,
                          float* __restrict__ av2) {
    int tid = threadIdx.x;
    int w = tid >> 6, lane = tid & 63;
    int t = lane & 15, gq = lane >> 4;
    char* KsBase = smem;                    // 2 x 8192 (Ks[1] doubles as Q staging)
    char* VsBase = smem + 16384;            // 8192
    char* Ps     = smem + 24576;            // 9216 (row stride 144)
    float* pws   = (float*)(smem + 33792);  // 2 x 128 f32

    int nt, mlo, mhi; float* avout;
    if (u < 6) { nt = u; mlo = 0; mhi = nt; avout = av0; }
    else if (u < 18) {
        int p = u - 6; nt = 6 + (p >> 1);
        int c0 = (nt + 2) >> 1;
        if (p & 1) { mlo = c0; mhi = nt; avout = av1; }
        else       { mlo = 0;  mhi = c0 - 1; avout = av0; }
    } else {
        int p = u - 18; int third = p / 3; nt = 12 + third; int q3 = p - 3 * third;
        int c = nt + 1, c1 = (c + 2) / 3, c2 = (2 * c + 2) / 3;
        if (q3 == 0)      { mlo = 0;  mhi = c1 - 1; avout = av0; }
        else if (q3 == 1) { mlo = c1; mhi = c2 - 1; avout = av1; }
        else              { mlo = c2; mhi = nt;     avout = av2; }
    }
    int n0 = nt << 6;

    const _Float16* qbase = uvqk + (size_t)b * NN * 2048 + 1024 + h * 64;
    const _Float16* kbase = uvqk + (size_t)b * NN * 2048 + 1536 + h * 64;
    const _Float16* vbase = vTg + (size_t)((b << 3) + h) * 64 * 1024;

    #pragma unroll
    for (int q = 0; q < 2; ++q) {
        int s = (((w << 1) + q) << 6) + lane;
        int r = s >> 3, cs = (s & 7) ^ (r & 7);
        gl16(qbase + (size_t)(n0 + r) * 2048 + (cs << 3), KsBase + 8192 + (((w << 1) + q) << 10));
        gl16(kbase + (size_t)((mlo << 6) + r) * 2048 + (cs << 3), KsBase + (((w << 1) + q) << 10));
    }
    if (tid < 128) pws[tid] = pw[(mlo << 6) - n0 + tid + 960];
    __syncthreads();

    h8 aq[2];
    {
        int rl = (w << 4) + t;
        #pragma unroll
        for (int ks = 0; ks < 2; ++ks)
            aq[ks] = *(const h8*)(KsBase + 8192 + rl * 128 + (((gq + (ks << 2)) ^ (rl & 7)) << 4));
    }
    asm volatile("s_waitcnt lgkmcnt(0)" ::: "memory");
    __builtin_amdgcn_sched_barrier(0);
    __syncthreads();   // all waves hold aq before Ks[1] overwritten by prefetch

    f4 zero4 = {0.0f, 0.0f, 0.0f, 0.0f};
    f4 avacc[4];
    #pragma unroll
    for (int j = 0; j < 4; ++j) avacc[j] = zero4;

    int cur = 0;
    for (int mt = mlo; mt <= mhi; ++mt) {
        int m0 = mt << 6;
        #pragma unroll
        for (int q = 0; q < 2; ++q) {
            int s = (((w << 1) + q) << 6) + lane;
            int r = s >> 3, cs = (s & 7) ^ (r & 7);
            gl16(vbase + (size_t)r * 1024 + m0 + (cs << 3), VsBase + (((w << 1) + q) << 10));
        }
        int mt2 = (mt < mhi) ? mt + 1 : mt;   // clamped: uniform vmcnt
        #pragma unroll
        for (int q = 0; q < 2; ++q) {
            int s = (((w << 1) + q) << 6) + lane;
            int r = s >> 3, cs = (s & 7) ^ (r & 7);
            gl16(kbase + (size_t)((mt2 << 6) + r) * 2048 + (cs << 3),
                 KsBase + ((cur ^ 1) << 13) + (((w << 1) + q) << 10));
        }
        if (tid < 128) pws[((cur ^ 1) << 7) + tid] = pw[(mt2 << 6) - n0 + tid + 960];

        const char* Kc = KsBase + (cur << 13);
        f4 sacc[4];
        __builtin_amdgcn_s_setprio(1);
        #pragma unroll
        for (int i = 0; i < 4; ++i) {
            f4 binit;
            #pragma unroll
            for (int rr = 0; rr < 4; ++rr)
                binit[rr] = pws[(cur << 7) + 63 + (i << 4) + (gq << 2) + rr - ((w << 4) + t)];
            int ml = (i << 4) + t;
            h8 ak0 = *(const h8*)(Kc + ml * 128 + (((gq + 0) ^ (ml & 7)) << 4));
            h8 ak1 = *(const h8*)(Kc + ml * 128 + (((gq + 4) ^ (ml & 7)) << 4));
            sacc[i] = __builtin_amdgcn_mfma_f32_16x16x32_f16(ak0, aq[0], binit, 0, 0, 0);
            sacc[i] = __builtin_amdgcn_mfma_f32_16x16x32_f16(ak1, aq[1], sacc[i], 0, 0, 0);
        }
        __builtin_amdgcn_s_setprio(0);
        int nabs = n0 + (w << 4) + t;
        #pragma unroll
        for (int i = 0; i < 4; ++i) {
            int mb = m0 + (i << 4) + (gq << 2);
            h4 pk;
            #pragma unroll
            for (int rr = 0; rr < 4; ++rr) {
                float p = (mb + rr <= nabs) ? fast_silu(sacc[i][rr]) : 0.0f;
                pk[rr] = (_Float16)p;
            }
            *(h4*)(Ps + ((w << 4) + t) * 144 + (i << 5) + (gq << 3)) = pk;
        }
        asm volatile("s_waitcnt lgkmcnt(0)" ::: "memory");
        asm volatile("s_waitcnt vmcnt(2)" ::: "memory");
        __builtin_amdgcn_s_barrier();
        __builtin_amdgcn_s_setprio(1);
        #pragma unroll
        for (int ks = 0; ks < 2; ++ks) {
            h8 pa = *(const h8*)(Ps + ((w << 4) + t) * 144 + (ks << 6) + (gq << 4));
            #pragma unroll
            for (int jt = 0; jt < 4; ++jt) {
                int dl = (jt << 4) + t;
                h8 bv = *(const h8*)(VsBase + dl * 128 + (((gq + (ks << 2)) ^ (dl & 7)) << 4));
                avacc[jt] = __builtin_amdgcn_mfma_f32_16x16x32_f16(pa, bv, avacc[jt], 0, 0, 0);
            }
        }
        __builtin_amdgcn_s_setprio(0);
        __syncthreads();
        cur ^= 1;
    }

    #pragma unroll
    for (int jt = 0; jt < 4; ++jt) {
        #pragma unroll
        for (int rr = 0; rr < 4; ++rr) {
            int n = n0 + (w << 4) + (gq << 2) + rr;
            int d = (jt << 4) + t;
            avout[(size_t)(b * NN + n) * 512 + h * 64 + d] = avacc[jt][rr] * (1.0f / 1024.0f);
        }
    }
}

// ================================================================ fallback wrappers
__global__ __launch_bounds__(256) void k_transpose16(const float* wuvqk, _Float16* wuT,
                                                     const float* wo, _Float16* woT) {
    __shared__ __align__(16) char smem[8448];
    transpose_unit(blockIdx.x, smem, wuvqk, wuT, wo, woT);
}

template<int MODE>
__global__ __launch_bounds__(256) void k_lnw(const float* X, const float* X2, const float* X3,
                                             const float* seq, const float* pos, const int* slen,
                                             const float* g, const float* bt,
                                             _Float16* O, const _Float16* U, float* Xw) {
    ln_unit<MODE>(blockIdx.x, X, X2, X3, seq, pos, slen, g, bt, O, U, Xw);
}

__global__ __launch_bounds__(256) void k_normw(float* X) { norm_unit(blockIdx.x, X); }

template<int EPI, int BM, int BN, int WAVES, int WGR, int WGC>
__global__ __launch_bounds__(WAVES * 64) void k_gemm(const _Float16* A, const _Float16* Bm,
                                                     _Float16* Cu, _Float16* vT,
                                                     const float* bo, const int* slen, float* Xio) {
    __shared__ __align__(16) char smem[(BM + BN) * 256];
    gemm_unit<EPI, BM, BN, WAVES, WGR, WGC>(blockIdx.y * gridDim.x + blockIdx.x, gridDim.x,
                                            gridDim.x * gridDim.y, smem, A, Bm, Cu, vT, bo, slen, Xio);
}

__global__ __launch_bounds__(256) void k_attn(const _Float16* uvqk, const _Float16* vT,
                                              const float* posw, float* av0, float* av1, float* av2) {
    __shared__ __align__(16) char smem[34816];
    int flat = blockIdx.x + 30 * (blockIdx.y + 8 * blockIdx.z);
    int f2 = (flat & 7) * 120 + (flat >> 3);
    int u = f2 % 30, h = (f2 / 30) & 7, b = f2 / 240;
    attn_unit(b, h, u, smem, uvqk, vT, posw, av0, av1, av2);
}

// ================================================================ cooperative mega kernel
struct MegaArgs {
    const float *seq, *pos, *ln1g, *ln1b, *ln2g, *ln2b, *wuvqk, *wo, *bo, *posw;
    const int* slen;
    float *x, *av0, *av1, *av2;
    _Float16 *nx, *oin, *uvqk, *vT, *wuT, *woT;
    unsigned int* ctr;
};

__global__ __launch_bounds__(256, 2) void k_mega(MegaArgs P) {
    cg::grid_group grid = cg::this_grid();
    __shared__ __align__(16) char smem[65536];
    int tid = threadIdx.x, bid = blockIdx.x, G = gridDim.x;

    // P0: reset queue counters, transpose weights, init + ln1(layer 0)
    if (bid == 0 && tid < 4) atomicExch(&P.ctr[tid], 0u);
    for (int u = bid; u < 1280; u += G)
        transpose_unit(u, smem, P.wuvqk, P.wuT, P.wo, P.woT);
    for (int vb = bid; vb < 512; vb += G)
        ln_unit<1>(vb, nullptr, nullptr, nullptr, P.seq, P.pos, P.slen, P.ln1g, P.ln1b,
                   P.nx, nullptr, P.x);
    grid.sync();

    for (int l = 0; l < NBL; ++l) {
        if (l > 0) {
            for (int vb = bid; vb < 512; vb += G)
                ln_unit<0>(vb, P.x, nullptr, nullptr, nullptr, nullptr, nullptr,
                           P.ln1g + l * 512, P.ln1b + l * 512, P.nx, nullptr, nullptr);
            grid.sync();
        }
        for (int u = bid; u < 512; u += G)
            gemm_unit<0, 128, 128, 4, 2, 2>(u, 16, 512, smem, P.nx,
                                            P.wuT + (size_t)l * 2048 * 512,
                                            P.uvqk, P.vT, nullptr, nullptr, nullptr);
        grid.sync();
        {
            volatile int* sm_u = (volatile int*)(smem + 35840);
            const float* pw = P.posw + l * 2047;
            for (;;) {
                __syncthreads();
                if (tid == 0) *sm_u = (int)atomicAdd(&P.ctr[l], 1u);
                __syncthreads();
                int p = *sm_u;
                if (p >= 960) break;
                int bh = p & 31;
                attn_unit(bh >> 3, bh & 7, c_order[p >> 5], smem, P.uvqk, P.vT, pw,
                          P.av0, P.av1, P.av2);
            }
        }
        grid.sync();
        for (int vb = bid; vb < 512; vb += G)
            ln_unit<2>(vb, P.av0, P.av1, P.av2, nullptr, nullptr, nullptr,
                       P.ln2g + l * 512, P.ln2b + l * 512, P.oin, P.uvqk, nullptr);
        grid.sync();
        for (int u = bid; u < 1024; u += G)
            gemm_unit<1, 64, 32, 4, 2, 2>(u, 16, 1024, smem, P.oin,
                                          P.woT + (size_t)l * 512 * 512,
                                          nullptr, nullptr, P.bo + l * 512, P.slen, P.x);
        grid.sync();
    }
    for (int vb = bid; vb < 512; vb += G)
        norm_unit(vb, P.x);
}

// ================================================================ launch
extern "C" void kernel_launch(void* const* d_in, const int* in_sizes, int n_in,
                              void* d_out, int out_size, void* d_ws, size_t ws_size,
                              hipStream_t stream) {
    char* W = (char*)d_ws;
    MegaArgs P;
    P.seq   = (const float*)d_in[0];
    P.slen  = (const int*)d_in[1];
    P.pos   = (const float*)d_in[2];
    P.ln1g  = (const float*)d_in[3];
    P.ln1b  = (const float*)d_in[4];
    P.wuvqk = (const float*)d_in[5];
    P.ln2g  = (const float*)d_in[6];
    P.ln2b  = (const float*)d_in[7];
    P.wo    = (const float*)d_in[8];
    P.bo    = (const float*)d_in[9];
    P.posw  = (const float*)d_in[10];
    P.x    = (float*)d_out;
    P.nx   = (_Float16*)(W);                    // 4 MiB
    P.oin  = (_Float16*)(W + (4u << 20));       // 4 MiB
    P.uvqk = (_Float16*)(W + (8u << 20));       // 16 MiB
    P.vT   = (_Float16*)(W + (24u << 20));      // 4 MiB [b][h][d][n]
    P.av0  = (float*)   (W + (28u << 20));      // 8 MiB
    P.av1  = (float*)   (W + (36u << 20));      // 8 MiB
    P.av2  = (float*)   (W + (44u << 20));      // 8 MiB
    P.wuT  = (_Float16*)(W + (52u << 20));      // 8 MiB [l][2048][512]
    P.woT  = (_Float16*)(W + (60u << 20));      // 2 MiB [l][512][512]
    P.ctr  = (unsigned int*)(W + (62u << 20));  // 4 queue counters

    bool done = false;
    int coopAttr = 0;
    if (hipDeviceGetAttribute(&coopAttr, hipDeviceAttributeCooperativeLaunch, 0) == hipSuccess &&
        coopAttr != 0) {
        int maxB = 0;
        if (hipOccupancyMaxActiveBlocksPerMultiprocessor(&maxB, (const void*)k_mega, 256, 0) ==
                hipSuccess && maxB >= 2) {
            void* kp[] = { &P };
            done = (hipLaunchCooperativeKernel((const void*)k_mega, dim3(512), dim3(256),
                                               kp, 0, stream) == hipSuccess);
        }
    }
    if (!done) {
        // R8-proven multi-launch fallback (identical unit math)
        k_transpose16<<<1280, 256, 0, stream>>>(P.wuvqk, P.wuT, P.wo, P.woT);
        for (int l = 0; l < NBL; ++l) {
            if (l == 0)
                k_lnw<1><<<512, 256, 0, stream>>>(nullptr, nullptr, nullptr, P.seq, P.pos, P.slen,
                                                  P.ln1g, P.ln1b, P.nx, nullptr, P.x);
            else
                k_lnw<0><<<512, 256, 0, stream>>>(P.x, nullptr, nullptr, nullptr, nullptr, nullptr,
                                                  P.ln1g + l * 512, P.ln1b + l * 512, P.nx,
                                                  nullptr, nullptr);
            k_gemm<0, 128, 128, 8, 2, 4><<<dim3(16, 32), 512, 0, stream>>>(
                P.nx, P.wuT + (size_t)l * 2048 * 512, P.uvqk, P.vT, nullptr, nullptr, nullptr);
            k_attn<<<dim3(30, 8, NBL), 256, 0, stream>>>(P.uvqk, P.vT, P.posw + l * 2047,
                                                         P.av0, P.av1, P.av2);
            k_lnw<2><<<512, 256, 0, stream>>>(P.av0, P.av1, P.av2, nullptr, nullptr, nullptr,
                                              P.ln2g + l * 512, P.ln2b + l * 512, P.oin,
                                              P.uvqk, nullptr);
            k_gemm<1, 64, 32, 4, 2, 2><<<dim3(16, 64), 256, 0, stream>>>(
                P.oin, P.woT + (size_t)l * 512 * 512, nullptr, nullptr, P.bo + l * 512,
                P.slen, P.x);
        }
        k_normw<<<512, 256, 0, stream>>>(P.x);
    }
}